// Round 7
// baseline (395.843 us; speedup 1.0000x reference)
//
#include <hip/hip_runtime.h>
#include <hip/hip_bf16.h>

#define NEG_SLOPE 0.2f
#define STATS_SPLIT 50

__device__ __forceinline__ unsigned short f2bf(float f) {
    unsigned int u = __float_as_uint(f);
    unsigned int r = (u + 0x7fffu + ((u >> 16) & 1u)) >> 16;
    return (unsigned short)r;
}
__device__ __forceinline__ float bf2f(unsigned short h) {
    return __uint_as_float(((unsigned int)h) << 16);
}

// ---------------------------------------------------------------------------
// K1: h = input @ W_fc  (N x 128) @ (128 x 128), fused el/er epilogue.
// 64-row tile, 4x8 acc/thread, split cols. Prefetch-to-reg pipelining:
// next chunk's global loads issue before current chunk's compute, so the
// vmcnt wait (at ds_write) lands after ~1024 FMAs of latency cover.
// h is written as PACKED BF16 (consumed only by the aggregate gather).
// ---------------------------------------------------------------------------
__global__ __launch_bounds__(256) void fc_gemm_kernel(
    const float* __restrict__ A, const float* __restrict__ W,
    const float* __restrict__ attn_l, const float* __restrict__ attn_r,
    unsigned short* __restrict__ h, float* __restrict__ el,
    float* __restrict__ er, int n)
{
    __shared__ float As[32][68];   // k-major: As[k][row]
    __shared__ float Bs[32][132];  // k-major: Bs[k][col]
    const int tid = threadIdx.x;
    const int tx = tid & 15;       // col quads: tx*4 and 64+tx*4
    const int ty = tid >> 4;       // rows ty*4 .. ty*4+3
    const int rowBase = blockIdx.x * 64;

    float acc[4][8];
#pragma unroll
    for (int i = 0; i < 4; ++i)
#pragma unroll
        for (int j = 0; j < 8; ++j) acc[i][j] = 0.f;

    float4 pa[2], pb[4];
    const int qA = tid & 7;          // k-quad for A stage (flat = it*256+tid)
    const int rA = tid >> 3;         // row (0..31) + it*32
    const int kB = tid >> 5;         // k for B stage (+ it*8)
    const int cB = tid & 31;         // col quad for B stage

#define FC_LOAD(ci)                                                          \
    {                                                                        \
        const int kc = (ci) * 32;                                            \
        _Pragma("unroll")                                                    \
        for (int it = 0; it < 2; ++it) {                                     \
            int row = rowBase + it * 32 + rA;                                \
            if (row >= n) row = n - 1;                                       \
            pa[it] = *(const float4*)&A[(long long)row * 128 + kc + qA * 4]; \
        }                                                                    \
        _Pragma("unroll")                                                    \
        for (int it = 0; it < 4; ++it) {                                     \
            pb[it] = *(const float4*)&W[(long long)(kc + it * 8 + kB) * 128  \
                                        + cB * 4];                           \
        }                                                                    \
    }

    FC_LOAD(0)
    for (int ci = 0; ci < 4; ++ci) {
        if (ci) __syncthreads();
#pragma unroll
        for (int it = 0; it < 2; ++it) {
            const int r = it * 32 + rA;
            As[qA * 4 + 0][r] = pa[it].x;
            As[qA * 4 + 1][r] = pa[it].y;
            As[qA * 4 + 2][r] = pa[it].z;
            As[qA * 4 + 3][r] = pa[it].w;
        }
#pragma unroll
        for (int it = 0; it < 4; ++it)
            *(float4*)&Bs[it * 8 + kB][cB * 4] = pb[it];
        __syncthreads();
        if (ci + 1 < 4) FC_LOAD(ci + 1)

#pragma unroll
        for (int k = 0; k < 32; ++k) {
            const float4 a  = *(const float4*)&As[k][ty * 4];
            const float4 b0 = *(const float4*)&Bs[k][tx * 4];
            const float4 b1 = *(const float4*)&Bs[k][64 + tx * 4];
            const float ar[4] = {a.x, a.y, a.z, a.w};
            const float br[8] = {b0.x, b0.y, b0.z, b0.w, b1.x, b1.y, b1.z, b1.w};
#pragma unroll
            for (int i = 0; i < 4; ++i)
#pragma unroll
                for (int j = 0; j < 8; ++j) acc[i][j] += ar[i] * br[j];
        }
    }
#undef FC_LOAD

    // epilogue: write h (bf16) + fused el/er from f32 accumulators.
    const float4 alA = *(const float4*)&attn_l[tx * 4];
    const float4 alB = *(const float4*)&attn_l[64 + tx * 4];
    const float4 arA = *(const float4*)&attn_r[tx * 4];
    const float4 arB = *(const float4*)&attn_r[64 + tx * 4];
#pragma unroll
    for (int i = 0; i < 4; ++i) {
        const int row = rowBase + ty * 4 + i;
        if (row >= n) break;
        const long long off = (long long)row * 128;
        const float4 o0 = {acc[i][0], acc[i][1], acc[i][2], acc[i][3]};
        const float4 o1 = {acc[i][4], acc[i][5], acc[i][6], acc[i][7]};
        ushort4 p0 = {f2bf(o0.x), f2bf(o0.y), f2bf(o0.z), f2bf(o0.w)};
        ushort4 p1 = {f2bf(o1.x), f2bf(o1.y), f2bf(o1.z), f2bf(o1.w)};
        *(ushort4*)&h[off + tx * 4] = p0;
        *(ushort4*)&h[off + 64 + tx * 4] = p1;
        float l0 = o0.x * alA.x + o0.y * alA.y + o0.z * alA.z + o0.w * alA.w;
        float l1 = o1.x * alB.x + o1.y * alB.y + o1.z * alB.z + o1.w * alB.w;
        float r0 = o0.x * arA.x + o0.y * arA.y + o0.z * arA.z + o0.w * arA.w;
        float r1 = o1.x * arB.x + o1.y * arB.y + o1.z * arB.z + o1.w * arB.w;
#pragma unroll
        for (int offx = 1; offx <= 2; offx <<= 1) {
            l0 += __shfl_xor(l0, offx, 64);
            l1 += __shfl_xor(l1, offx, 64);
            r0 += __shfl_xor(r0, offx, 64);
            r1 += __shfl_xor(r1, offx, 64);
        }
        if ((tx & 3) == 0) {
            const int hd = tx >> 2;
            el[(long long)row * 8 + hd] = l0;
            el[(long long)row * 8 + 4 + hd] = l1;
            er[(long long)row * 8 + hd] = r0;
            er[(long long)row * 8 + 4 + hd] = r1;
        }
    }
}

// ---------------------------------------------------------------------------
// CSR build: histogram -> 2-level exclusive scan -> scatter src ids by dst.
// ---------------------------------------------------------------------------
__global__ __launch_bounds__(256) void hist_kernel(
    const int* __restrict__ dst, int* __restrict__ deg, int E)
{
    const int i = blockIdx.x * 256 + threadIdx.x;
    if (i < E) atomicAdd(&deg[dst[i]], 1);
}

__global__ __launch_bounds__(256) void scan1_kernel(
    const int* __restrict__ deg, int* __restrict__ row,
    int* __restrict__ blockSums, int n)
{
    __shared__ int sdata[256];
    const int t = threadIdx.x;
    const int base = blockIdx.x * 1024 + t * 4;
    int v[4];
    int tot = 0;
#pragma unroll
    for (int j = 0; j < 4; ++j) {
        v[j] = (base + j < n) ? deg[base + j] : 0;
        tot += v[j];
    }
    sdata[t] = tot;
    __syncthreads();
    for (int off = 1; off < 256; off <<= 1) {
        const int x = (t >= off) ? sdata[t - off] : 0;
        __syncthreads();
        sdata[t] += x;
        __syncthreads();
    }
    if (t == 255) blockSums[blockIdx.x] = sdata[255];
    int run = sdata[t] - tot;
#pragma unroll
    for (int j = 0; j < 4; ++j) {
        if (base + j < n) row[base + j] = run;
        run += v[j];
    }
}

__global__ __launch_bounds__(128) void scan2_kernel(
    int* __restrict__ blockSums, int nb)
{
    __shared__ int sdata[128];
    const int t = threadIdx.x;
    const int v = (t < nb) ? blockSums[t] : 0;
    sdata[t] = v;
    __syncthreads();
    for (int off = 1; off < 128; off <<= 1) {
        const int x = (t >= off) ? sdata[t - off] : 0;
        __syncthreads();
        sdata[t] += x;
        __syncthreads();
    }
    if (t < nb) blockSums[t] = sdata[t] - v;
}

__global__ __launch_bounds__(256) void scan3_kernel(
    int* __restrict__ row, int* __restrict__ cursor,
    const int* __restrict__ blockSums, int n, int E)
{
    const int i = blockIdx.x * 256 + threadIdx.x;
    if (i == 0) row[n] = E;
    if (i >= n) return;
    const int r = row[i] + blockSums[i >> 10];
    row[i] = r;
    cursor[i] = r;
}

__global__ __launch_bounds__(256) void scatter_kernel(
    const int* __restrict__ src, const int* __restrict__ dst,
    int* __restrict__ cursor, int* __restrict__ srcs, int E)
{
    const int i = blockIdx.x * 256 + threadIdx.x;
    if (i >= E) return;
    const int pos = atomicAdd(&cursor[dst[i]], 1);
    srcs[pos] = src[i];
}

// ---------------------------------------------------------------------------
// K3: aggregate. One wave per dst node, 2 features/lane, local softmax,
// no atomics. h gathered as bf16 (halves the dominant gather traffic).
// ---------------------------------------------------------------------------
__global__ __launch_bounds__(256) void aggregate_kernel(
    const float* __restrict__ el, const float* __restrict__ er,
    const unsigned short* __restrict__ h, const int* __restrict__ row,
    const int* __restrict__ srcs, float* __restrict__ rst, int n)
{
    const int wave = blockIdx.x * 4 + (threadIdx.x >> 6);
    const int lane = threadIdx.x & 63;
    if (wave >= n) return;
    const int d = wave;
    const int start = row[d], end = row[d + 1];
    const int hd0 = lane >> 4;
    const float er0 = er[(long long)d * 8 + hd0];
    const float er1 = er[(long long)d * 8 + hd0 + 4];

    float acc0 = 0.f, acc1 = 0.f, den0 = 0.f, den1 = 0.f;
    for (int p = start; p < end; ++p) {
        const int s = srcs[p];
        float e0 = el[(long long)s * 8 + hd0] + er0;
        float e1 = el[(long long)s * 8 + hd0 + 4] + er1;
        e0 = e0 >= 0.f ? e0 : NEG_SLOPE * e0;
        e1 = e1 >= 0.f ? e1 : NEG_SLOPE * e1;
        const float w0 = __expf(e0);
        const float w1 = __expf(e1);
        den0 += w0; den1 += w1;
        acc0 += w0 * bf2f(h[(long long)s * 128 + lane]);
        acc1 += w1 * bf2f(h[(long long)s * 128 + 64 + lane]);
    }
    const float r0 = (end > start) ? acc0 / den0 : 0.f;
    const float r1 = (end > start) ? acc1 / den1 : 0.f;
    rst[(long long)d * 128 + lane] = r0;
    rst[(long long)d * 128 + 64 + lane] = r1;
}

// ---------------------------------------------------------------------------
// K4: GCNII combine, K=256 (concat(rst+bias, h0)). 64-row tile, 4x8 acc,
// split cols, prefetch-to-reg pipelining. Epilogue re-reads rst/h0/input.
// ---------------------------------------------------------------------------
__global__ __launch_bounds__(256) void combine_gemm_kernel(
    const float* __restrict__ rst, const float* __restrict__ gat_bias,
    const float* __restrict__ h0, const float* __restrict__ input,
    const float* __restrict__ W, const int* __restrict__ l_p,
    const float* __restrict__ lamda_p, const float* __restrict__ alpha_p,
    float* __restrict__ x, int n)
{
    __shared__ float As[32][68];
    __shared__ float Bs[32][132];
    const int tid = threadIdx.x;
    const int tx = tid & 15;
    const int ty = tid >> 4;
    const int rowBase = blockIdx.x * 64;

    float acc[4][8];
#pragma unroll
    for (int i = 0; i < 4; ++i)
#pragma unroll
        for (int j = 0; j < 8; ++j) acc[i][j] = 0.f;

    float4 pa[2], pb[4];
    const int qA = tid & 7;
    const int rA = tid >> 3;
    const int kB = tid >> 5;
    const int cB = tid & 31;

#define CB_LOAD(ci)                                                           \
    {                                                                         \
        const int kc = (ci) * 32;                                             \
        const int koff = kc & 127;                                            \
        const bool first = (ci) < 4;                                          \
        _Pragma("unroll")                                                     \
        for (int it = 0; it < 2; ++it) {                                      \
            int row = rowBase + it * 32 + rA;                                 \
            if (row >= n) row = n - 1;                                        \
            if (first) {                                                      \
                float4 v = *(const float4*)&rst[(long long)row * 128 + koff   \
                                                + qA * 4];                    \
                const float4 b = *(const float4*)&gat_bias[koff + qA * 4];    \
                v.x += b.x; v.y += b.y; v.z += b.z; v.w += b.w;               \
                pa[it] = v;                                                   \
            } else {                                                          \
                pa[it] = *(const float4*)&h0[(long long)row * 128 + koff      \
                                             + qA * 4];                       \
            }                                                                 \
        }                                                                     \
        _Pragma("unroll")                                                     \
        for (int it = 0; it < 4; ++it) {                                      \
            pb[it] = *(const float4*)&W[(long long)(kc + it * 8 + kB) * 128   \
                                        + cB * 4];                            \
        }                                                                     \
    }

    CB_LOAD(0)
    for (int ci = 0; ci < 8; ++ci) {
        if (ci) __syncthreads();
#pragma unroll
        for (int it = 0; it < 2; ++it) {
            const int r = it * 32 + rA;
            As[qA * 4 + 0][r] = pa[it].x;
            As[qA * 4 + 1][r] = pa[it].y;
            As[qA * 4 + 2][r] = pa[it].z;
            As[qA * 4 + 3][r] = pa[it].w;
        }
#pragma unroll
        for (int it = 0; it < 4; ++it)
            *(float4*)&Bs[it * 8 + kB][cB * 4] = pb[it];
        __syncthreads();
        if (ci + 1 < 8) CB_LOAD(ci + 1)

#pragma unroll
        for (int k = 0; k < 32; ++k) {
            const float4 a  = *(const float4*)&As[k][ty * 4];
            const float4 b0 = *(const float4*)&Bs[k][tx * 4];
            const float4 b1 = *(const float4*)&Bs[k][64 + tx * 4];
            const float ar[4] = {a.x, a.y, a.z, a.w};
            const float br[8] = {b0.x, b0.y, b0.z, b0.w, b1.x, b1.y, b1.z, b1.w};
#pragma unroll
            for (int i = 0; i < 4; ++i)
#pragma unroll
                for (int j = 0; j < 8; ++j) acc[i][j] += ar[i] * br[j];
        }
    }
#undef CB_LOAD

    const float alpha = alpha_p[0];
    const float theta = fminf(1.0f, logf(lamda_p[0] / (float)l_p[0] + 1.0f));
    const float c1 = (1.f - theta) * (1.f - alpha);
    const float c2 = (1.f - theta) * alpha;
    const float4 bias0 = *(const float4*)&gat_bias[tx * 4];
    const float4 bias1 = *(const float4*)&gat_bias[64 + tx * 4];

#pragma unroll
    for (int i = 0; i < 4; ++i) {
        const int row = rowBase + ty * 4 + i;
        if (row >= n) break;
        const long long off = (long long)row * 128;
        const float4 rs0 = *(const float4*)&rst[off + tx * 4];
        const float4 rs1 = *(const float4*)&rst[off + 64 + tx * 4];
        const float4 h00 = *(const float4*)&h0[off + tx * 4];
        const float4 h01 = *(const float4*)&h0[off + 64 + tx * 4];
        const float4 in0 = *(const float4*)&input[off + tx * 4];
        const float4 in1 = *(const float4*)&input[off + 64 + tx * 4];
        float4 o0, o1;
        o0.x = theta * acc[i][0] + c1 * (rs0.x + bias0.x) + c2 * h00.x + in0.x;
        o0.y = theta * acc[i][1] + c1 * (rs0.y + bias0.y) + c2 * h00.y + in0.y;
        o0.z = theta * acc[i][2] + c1 * (rs0.z + bias0.z) + c2 * h00.z + in0.z;
        o0.w = theta * acc[i][3] + c1 * (rs0.w + bias0.w) + c2 * h00.w + in0.w;
        o1.x = theta * acc[i][4] + c1 * (rs1.x + bias1.x) + c2 * h01.x + in1.x;
        o1.y = theta * acc[i][5] + c1 * (rs1.y + bias1.y) + c2 * h01.y + in1.y;
        o1.z = theta * acc[i][6] + c1 * (rs1.z + bias1.z) + c2 * h01.z + in1.z;
        o1.w = theta * acc[i][7] + c1 * (rs1.w + bias1.w) + c2 * h01.w + in1.w;
        *(float4*)&x[off + tx * 4] = o0;
        *(float4*)&x[off + 64 + tx * 4] = o1;
    }
}

// ---------------------------------------------------------------------------
// K5: per-subgraph partial sums (split over nodes, atomics into (B,128)).
// ---------------------------------------------------------------------------
__global__ __launch_bounds__(128) void stats_kernel(
    const float* __restrict__ x, const int* __restrict__ cums,
    float* __restrict__ sums, float* __restrict__ sumsq)
{
    const int b = blockIdx.x / STATS_SPLIT;
    const int part = blockIdx.x % STATS_SPLIT;
    const int tid = threadIdx.x;
    const int start = cums[b], end = cums[b + 1];
    float s = 0.f, s2 = 0.f;
    for (int node = start + part; node < end; node += STATS_SPLIT) {
        const float v = x[(long long)node * 128 + tid];
        s += v;
        s2 += v * v;
    }
    atomicAdd(&sums[b * 128 + tid], s);
    atomicAdd(&sumsq[b * 128 + tid], s2);
}

__global__ __launch_bounds__(128) void finalize_stats_kernel(
    const int* __restrict__ cums, float* __restrict__ sums,
    float* __restrict__ sumsq)
{
    const int b = blockIdx.x;
    const int tid = threadIdx.x;
    const float cnt = (float)(cums[b + 1] - cums[b]);
    const float s = sums[b * 128 + tid];
    const float s2 = sumsq[b * 128 + tid];
    const float mean = s / cnt;
    float var = (s2 - s * mean) / (cnt - 1.f);
    var = fmaxf(var, 0.f);
    sums[b * 128 + tid] = mean;
    sumsq[b * 128 + tid] = 1.f / (sqrtf(var) + 1e-5f);
}

__global__ __launch_bounds__(256) void norm_kernel(
    const float* __restrict__ x, const float* __restrict__ mean,
    const float* __restrict__ istd, const int* __restrict__ cums, int nb,
    const float* __restrict__ gamma, const float* __restrict__ beta,
    float* __restrict__ out, int n)
{
    const long long gid = (long long)blockIdx.x * 256 + threadIdx.x;
    const int node = (int)(gid >> 5);
    if (node >= n) return;
    const int f4 = (int)(gid & 31);
    int lo = 0, hi = nb;
    while (hi - lo > 1) {
        const int mid = (lo + hi) >> 1;
        if (cums[mid] <= node) lo = mid; else hi = mid;
    }
    const float4 m = *(const float4*)&mean[lo * 128 + f4 * 4];
    const float4 is = *(const float4*)&istd[lo * 128 + f4 * 4];
    const float4 g = *(const float4*)&gamma[f4 * 4];
    const float4 bt = *(const float4*)&beta[f4 * 4];
    const float4 v = *(const float4*)&x[(long long)node * 128 + f4 * 4];
    float4 o;
    o.x = g.x * ((v.x - m.x) * is.x) + bt.x;
    o.y = g.y * ((v.y - m.y) * is.y) + bt.y;
    o.z = g.z * ((v.z - m.z) * is.z) + bt.z;
    o.w = g.w * ((v.w - m.w) * is.w) + bt.w;
    *(float4*)&out[(long long)node * 128 + f4 * 4] = o;
}

// ---------------------------------------------------------------------------
extern "C" void kernel_launch(void* const* d_in, const int* in_sizes, int n_in,
                              void* d_out, int out_size, void* d_ws, size_t ws_size,
                              hipStream_t stream) {
    const float* input   = (const float*)d_in[0];
    const float* h0      = (const float*)d_in[1];
    const int*   src     = (const int*)d_in[2];
    const int*   dst     = (const int*)d_in[3];
    const int*   cums    = (const int*)d_in[4];
    const int*   l_p     = (const int*)d_in[5];
    const float* lamda_p = (const float*)d_in[6];
    const float* alpha_p = (const float*)d_in[7];
    const float* W_fc    = (const float*)d_in[8];
    const float* attn_l  = (const float*)d_in[9];
    const float* attn_r  = (const float*)d_in[10];
    const float* gat_bias= (const float*)d_in[11];
    const float* W_comb  = (const float*)d_in[12];
    const float* gamma   = (const float*)d_in[13];
    const float* beta    = (const float*)d_in[14];

    const int n  = in_sizes[0] / 128;
    const int E  = in_sizes[2];
    const int nb = in_sizes[4] - 1;
    float* out = (float*)d_out;

    // workspace layout
    char* ws = (char*)d_ws;
    size_t o = 0;
    unsigned short* h = (unsigned short*)(ws + o); o += (size_t)n * 128 * 2;
    float* el       = (float*)(ws + o); o += (size_t)n * 8 * 4;
    float* er       = (float*)(ws + o); o += (size_t)n * 8 * 4;
    float* rst      = (float*)(ws + o); o += (size_t)n * 128 * 4;
    float* sums     = (float*)(ws + o); o += (size_t)nb * 128 * 4;
    float* sumsq    = (float*)(ws + o); o += (size_t)nb * 128 * 4;
    int* deg        = (int*)(ws + o);   o += (size_t)n * 4;
    int* row_ptr    = (int*)(ws + o);   o += (size_t)(n + 1) * 4;
    int* cursor     = (int*)(ws + o);   o += (size_t)n * 4;
    int* blockSums  = (int*)(ws + o);   o += 128 * 4;
    int* srcs       = (int*)(ws + o);   o += (size_t)E * 4;

    hipMemsetAsync(deg, 0, (size_t)n * 4, stream);
    hipMemsetAsync(sums, 0, (size_t)nb * 128 * 4 * 2, stream);

    // --- CSR build ---
    hist_kernel<<<(E + 255) / 256, 256, 0, stream>>>(dst, deg, E);
    const int nblk1 = (n + 1023) / 1024;
    scan1_kernel<<<nblk1, 256, 0, stream>>>(deg, row_ptr, blockSums, n);
    scan2_kernel<<<1, 128, 0, stream>>>(blockSums, nblk1);
    scan3_kernel<<<(n + 255) / 256, 256, 0, stream>>>(row_ptr, cursor, blockSums, n, E);
    scatter_kernel<<<(E + 255) / 256, 256, 0, stream>>>(src, dst, cursor, srcs, E);

    // --- dense pipeline ---
    const int gemm_grid = (n + 63) / 64;
    fc_gemm_kernel<<<gemm_grid, 256, 0, stream>>>(
        input, W_fc, attn_l, attn_r, h, el, er, n);

    aggregate_kernel<<<(n + 3) / 4, 256, 0, stream>>>(
        el, er, h, row_ptr, srcs, rst, n);

    combine_gemm_kernel<<<gemm_grid, 256, 0, stream>>>(
        rst, gat_bias, h0, input, W_comb, l_p, lamda_p, alpha_p, out, n);

    stats_kernel<<<nb * STATS_SPLIT, 128, 0, stream>>>(out, cums, sums, sumsq);
    finalize_stats_kernel<<<nb, 128, 0, stream>>>(cums, sums, sumsq);

    const long long norm_threads = (long long)n * 32;
    norm_kernel<<<(int)((norm_threads + 255) / 256), 256, 0, stream>>>(
        out, sums, sumsq, cums, nb, gamma, beta, out, n);
}

// Round 8
// 342.166 us; speedup vs baseline: 1.1569x; 1.1569x over previous
//
#include <hip/hip_runtime.h>
#include <hip/hip_bf16.h>

#define NEG_SLOPE 0.2f
#define STATS_SPLIT 50

__device__ __forceinline__ unsigned short f2bf(float f) {
    unsigned int u = __float_as_uint(f);
    unsigned int r = (u + 0x7fffu + ((u >> 16) & 1u)) >> 16;
    return (unsigned short)r;
}
__device__ __forceinline__ float bf2f(unsigned short h) {
    return __uint_as_float(((unsigned int)h) << 16);
}

// ---------------------------------------------------------------------------
// K1: h = input @ W_fc  (N x 128) @ (128 x 128), fused el/er epilogue.
// 64-row tile, 4x8 acc/thread, split cols (tx*4, 64+tx*4). Simple
// stage-then-compute (reg-prefetch regressed: -20 VGPR occupancy loss
// outweighed latency cover -- round 7 post-mortem). h written as bf16.
// ---------------------------------------------------------------------------
__global__ __launch_bounds__(256) void fc_gemm_kernel(
    const float* __restrict__ A, const float* __restrict__ W,
    const float* __restrict__ attn_l, const float* __restrict__ attn_r,
    unsigned short* __restrict__ h, float* __restrict__ el,
    float* __restrict__ er, int n)
{
    __shared__ float As[32][68];   // k-major: As[k][row]
    __shared__ float Bs[32][132];  // k-major: Bs[k][col]
    const int tid = threadIdx.x;
    const int tx = tid & 15;
    const int ty = tid >> 4;
    const int rowBase = blockIdx.x * 64;

    float acc[4][8];
#pragma unroll
    for (int i = 0; i < 4; ++i)
#pragma unroll
        for (int j = 0; j < 8; ++j) acc[i][j] = 0.f;

    for (int ci = 0; ci < 4; ++ci) {
        const int kc = ci * 32;
        // stage A: 64 rows x 32 k (512 float4, 2/thread), transposed store
#pragma unroll
        for (int it = 0; it < 2; ++it) {
            const int flat = it * 256 + tid;
            const int q = flat & 7;
            const int r = flat >> 3;
            int row = rowBase + r;
            if (row >= n) row = n - 1;
            const float4 v = *(const float4*)&A[(long long)row * 128 + kc + q * 4];
            As[q * 4 + 0][r] = v.x;
            As[q * 4 + 1][r] = v.y;
            As[q * 4 + 2][r] = v.z;
            As[q * 4 + 3][r] = v.w;
        }
        // stage B: 32 k x 128 cols (1024 float4, 4/thread)
#pragma unroll
        for (int it = 0; it < 4; ++it) {
            const int flat = it * 256 + tid;
            const int k = flat >> 5;
            const int c4 = flat & 31;
            *(float4*)&Bs[k][c4 * 4] =
                *(const float4*)&W[(long long)(kc + k) * 128 + c4 * 4];
        }
        __syncthreads();

#pragma unroll
        for (int k = 0; k < 32; ++k) {
            const float4 a  = *(const float4*)&As[k][ty * 4];
            const float4 b0 = *(const float4*)&Bs[k][tx * 4];
            const float4 b1 = *(const float4*)&Bs[k][64 + tx * 4];
            const float ar[4] = {a.x, a.y, a.z, a.w};
            const float br[8] = {b0.x, b0.y, b0.z, b0.w, b1.x, b1.y, b1.z, b1.w};
#pragma unroll
            for (int i = 0; i < 4; ++i)
#pragma unroll
                for (int j = 0; j < 8; ++j) acc[i][j] += ar[i] * br[j];
        }
        __syncthreads();
    }

    // epilogue: write h (bf16) + fused el/er from f32 accumulators.
    const float4 alA = *(const float4*)&attn_l[tx * 4];
    const float4 alB = *(const float4*)&attn_l[64 + tx * 4];
    const float4 arA = *(const float4*)&attn_r[tx * 4];
    const float4 arB = *(const float4*)&attn_r[64 + tx * 4];
#pragma unroll
    for (int i = 0; i < 4; ++i) {
        const int row = rowBase + ty * 4 + i;
        if (row >= n) break;
        const long long off = (long long)row * 128;
        const float4 o0 = {acc[i][0], acc[i][1], acc[i][2], acc[i][3]};
        const float4 o1 = {acc[i][4], acc[i][5], acc[i][6], acc[i][7]};
        ushort4 p0 = {f2bf(o0.x), f2bf(o0.y), f2bf(o0.z), f2bf(o0.w)};
        ushort4 p1 = {f2bf(o1.x), f2bf(o1.y), f2bf(o1.z), f2bf(o1.w)};
        *(ushort4*)&h[off + tx * 4] = p0;
        *(ushort4*)&h[off + 64 + tx * 4] = p1;
        float l0 = o0.x * alA.x + o0.y * alA.y + o0.z * alA.z + o0.w * alA.w;
        float l1 = o1.x * alB.x + o1.y * alB.y + o1.z * alB.z + o1.w * alB.w;
        float r0 = o0.x * arA.x + o0.y * arA.y + o0.z * arA.z + o0.w * arA.w;
        float r1 = o1.x * arB.x + o1.y * arB.y + o1.z * arB.z + o1.w * arB.w;
#pragma unroll
        for (int offx = 1; offx <= 2; offx <<= 1) {
            l0 += __shfl_xor(l0, offx, 64);
            l1 += __shfl_xor(l1, offx, 64);
            r0 += __shfl_xor(r0, offx, 64);
            r1 += __shfl_xor(r1, offx, 64);
        }
        if ((tx & 3) == 0) {
            const int hd = tx >> 2;
            el[(long long)row * 8 + hd] = l0;
            el[(long long)row * 8 + 4 + hd] = l1;
            er[(long long)row * 8 + hd] = r0;
            er[(long long)row * 8 + 4 + hd] = r1;
        }
    }
}

// ---------------------------------------------------------------------------
// CSR build: histogram -> 2-level exclusive scan -> scatter src ids by dst.
// ---------------------------------------------------------------------------
__global__ __launch_bounds__(256) void hist_kernel(
    const int* __restrict__ dst, int* __restrict__ deg, int E)
{
    const int i = blockIdx.x * 256 + threadIdx.x;
    if (i < E) atomicAdd(&deg[dst[i]], 1);
}

__global__ __launch_bounds__(256) void scan1_kernel(
    const int* __restrict__ deg, int* __restrict__ row,
    int* __restrict__ blockSums, int n)
{
    __shared__ int sdata[256];
    const int t = threadIdx.x;
    const int base = blockIdx.x * 1024 + t * 4;
    int v[4];
    int tot = 0;
#pragma unroll
    for (int j = 0; j < 4; ++j) {
        v[j] = (base + j < n) ? deg[base + j] : 0;
        tot += v[j];
    }
    sdata[t] = tot;
    __syncthreads();
    for (int off = 1; off < 256; off <<= 1) {
        const int x = (t >= off) ? sdata[t - off] : 0;
        __syncthreads();
        sdata[t] += x;
        __syncthreads();
    }
    if (t == 255) blockSums[blockIdx.x] = sdata[255];
    int run = sdata[t] - tot;
#pragma unroll
    for (int j = 0; j < 4; ++j) {
        if (base + j < n) row[base + j] = run;
        run += v[j];
    }
}

__global__ __launch_bounds__(128) void scan2_kernel(
    int* __restrict__ blockSums, int nb)
{
    __shared__ int sdata[128];
    const int t = threadIdx.x;
    const int v = (t < nb) ? blockSums[t] : 0;
    sdata[t] = v;
    __syncthreads();
    for (int off = 1; off < 128; off <<= 1) {
        const int x = (t >= off) ? sdata[t - off] : 0;
        __syncthreads();
        sdata[t] += x;
        __syncthreads();
    }
    if (t < nb) blockSums[t] = sdata[t] - v;
}

__global__ __launch_bounds__(256) void scan3_kernel(
    int* __restrict__ row, int* __restrict__ cursor,
    const int* __restrict__ blockSums, int n, int E)
{
    const int i = blockIdx.x * 256 + threadIdx.x;
    if (i == 0) row[n] = E;
    if (i >= n) return;
    const int r = row[i] + blockSums[i >> 10];
    row[i] = r;
    cursor[i] = r;
}

__global__ __launch_bounds__(256) void scatter_kernel(
    const int* __restrict__ src, const int* __restrict__ dst,
    int* __restrict__ cursor, int* __restrict__ srcs, int E)
{
    const int i = blockIdx.x * 256 + threadIdx.x;
    if (i >= E) return;
    const int pos = atomicAdd(&cursor[dst[i]], 1);
    srcs[pos] = src[i];
}

// ---------------------------------------------------------------------------
// K3: aggregate. One wave per dst node, 2 features/lane, local softmax,
// no atomics. h gathered as bf16 (halves the dominant gather traffic).
// ---------------------------------------------------------------------------
__global__ __launch_bounds__(256) void aggregate_kernel(
    const float* __restrict__ el, const float* __restrict__ er,
    const unsigned short* __restrict__ h, const int* __restrict__ row,
    const int* __restrict__ srcs, float* __restrict__ rst, int n)
{
    const int wave = blockIdx.x * 4 + (threadIdx.x >> 6);
    const int lane = threadIdx.x & 63;
    if (wave >= n) return;
    const int d = wave;
    const int start = row[d], end = row[d + 1];
    const int hd0 = lane >> 4;
    const float er0 = er[(long long)d * 8 + hd0];
    const float er1 = er[(long long)d * 8 + hd0 + 4];

    float acc0 = 0.f, acc1 = 0.f, den0 = 0.f, den1 = 0.f;
    for (int p = start; p < end; ++p) {
        const int s = srcs[p];
        float e0 = el[(long long)s * 8 + hd0] + er0;
        float e1 = el[(long long)s * 8 + hd0 + 4] + er1;
        e0 = e0 >= 0.f ? e0 : NEG_SLOPE * e0;
        e1 = e1 >= 0.f ? e1 : NEG_SLOPE * e1;
        const float w0 = __expf(e0);
        const float w1 = __expf(e1);
        den0 += w0; den1 += w1;
        acc0 += w0 * bf2f(h[(long long)s * 128 + lane]);
        acc1 += w1 * bf2f(h[(long long)s * 128 + 64 + lane]);
    }
    const float r0 = (end > start) ? acc0 / den0 : 0.f;
    const float r1 = (end > start) ? acc1 / den1 : 0.f;
    rst[(long long)d * 128 + lane] = r0;
    rst[(long long)d * 128 + 64 + lane] = r1;
}

// ---------------------------------------------------------------------------
// K4: GCNII combine, K=256 (concat(rst+bias, h0)). 64-row tile, 4x8 acc,
// split cols, simple stage-then-compute (round-6 structure: 107 us,
// VGPR 56, zero spill). Epilogue re-reads rst/h0/input (L2/LLC-warm).
// ---------------------------------------------------------------------------
__global__ __launch_bounds__(256) void combine_gemm_kernel(
    const float* __restrict__ rst, const float* __restrict__ gat_bias,
    const float* __restrict__ h0, const float* __restrict__ input,
    const float* __restrict__ W, const int* __restrict__ l_p,
    const float* __restrict__ lamda_p, const float* __restrict__ alpha_p,
    float* __restrict__ x, int n)
{
    __shared__ float As[32][68];
    __shared__ float Bs[32][132];
    const int tid = threadIdx.x;
    const int tx = tid & 15;
    const int ty = tid >> 4;
    const int rowBase = blockIdx.x * 64;

    float acc[4][8];
#pragma unroll
    for (int i = 0; i < 4; ++i)
#pragma unroll
        for (int j = 0; j < 8; ++j) acc[i][j] = 0.f;

    for (int ci = 0; ci < 8; ++ci) {
        const int kc = ci * 32;
        const int koff = kc & 127;
        const bool first = ci < 4;
#pragma unroll
        for (int it = 0; it < 2; ++it) {
            const int flat = it * 256 + tid;
            const int q = flat & 7;
            const int r = flat >> 3;
            int row = rowBase + r;
            if (row >= n) row = n - 1;
            float4 v;
            if (first) {
                v = *(const float4*)&rst[(long long)row * 128 + koff + q * 4];
                const float4 b = *(const float4*)&gat_bias[koff + q * 4];
                v.x += b.x; v.y += b.y; v.z += b.z; v.w += b.w;
            } else {
                v = *(const float4*)&h0[(long long)row * 128 + koff + q * 4];
            }
            As[q * 4 + 0][r] = v.x;
            As[q * 4 + 1][r] = v.y;
            As[q * 4 + 2][r] = v.z;
            As[q * 4 + 3][r] = v.w;
        }
#pragma unroll
        for (int it = 0; it < 4; ++it) {
            const int flat = it * 256 + tid;
            const int k = flat >> 5;
            const int c4 = flat & 31;
            *(float4*)&Bs[k][c4 * 4] =
                *(const float4*)&W[(long long)(kc + k) * 128 + c4 * 4];
        }
        __syncthreads();

#pragma unroll
        for (int k = 0; k < 32; ++k) {
            const float4 a  = *(const float4*)&As[k][ty * 4];
            const float4 b0 = *(const float4*)&Bs[k][tx * 4];
            const float4 b1 = *(const float4*)&Bs[k][64 + tx * 4];
            const float ar[4] = {a.x, a.y, a.z, a.w};
            const float br[8] = {b0.x, b0.y, b0.z, b0.w, b1.x, b1.y, b1.z, b1.w};
#pragma unroll
            for (int i = 0; i < 4; ++i)
#pragma unroll
                for (int j = 0; j < 8; ++j) acc[i][j] += ar[i] * br[j];
        }
        __syncthreads();
    }

    const float alpha = alpha_p[0];
    const float theta = fminf(1.0f, logf(lamda_p[0] / (float)l_p[0] + 1.0f));
    const float c1 = (1.f - theta) * (1.f - alpha);
    const float c2 = (1.f - theta) * alpha;
    const float4 bias0 = *(const float4*)&gat_bias[tx * 4];
    const float4 bias1 = *(const float4*)&gat_bias[64 + tx * 4];

#pragma unroll
    for (int i = 0; i < 4; ++i) {
        const int row = rowBase + ty * 4 + i;
        if (row >= n) break;
        const long long off = (long long)row * 128;
        const float4 rs0 = *(const float4*)&rst[off + tx * 4];
        const float4 rs1 = *(const float4*)&rst[off + 64 + tx * 4];
        const float4 h00 = *(const float4*)&h0[off + tx * 4];
        const float4 h01 = *(const float4*)&h0[off + 64 + tx * 4];
        const float4 in0 = *(const float4*)&input[off + tx * 4];
        const float4 in1 = *(const float4*)&input[off + 64 + tx * 4];
        float4 o0, o1;
        o0.x = theta * acc[i][0] + c1 * (rs0.x + bias0.x) + c2 * h00.x + in0.x;
        o0.y = theta * acc[i][1] + c1 * (rs0.y + bias0.y) + c2 * h00.y + in0.y;
        o0.z = theta * acc[i][2] + c1 * (rs0.z + bias0.z) + c2 * h00.z + in0.z;
        o0.w = theta * acc[i][3] + c1 * (rs0.w + bias0.w) + c2 * h00.w + in0.w;
        o1.x = theta * acc[i][4] + c1 * (rs1.x + bias1.x) + c2 * h01.x + in1.x;
        o1.y = theta * acc[i][5] + c1 * (rs1.y + bias1.y) + c2 * h01.y + in1.y;
        o1.z = theta * acc[i][6] + c1 * (rs1.z + bias1.z) + c2 * h01.z + in1.z;
        o1.w = theta * acc[i][7] + c1 * (rs1.w + bias1.w) + c2 * h01.w + in1.w;
        *(float4*)&x[off + tx * 4] = o0;
        *(float4*)&x[off + 64 + tx * 4] = o1;
    }
}

// ---------------------------------------------------------------------------
// K5: per-subgraph partial sums (split over nodes, atomics into (B,128)).
// ---------------------------------------------------------------------------
__global__ __launch_bounds__(128) void stats_kernel(
    const float* __restrict__ x, const int* __restrict__ cums,
    float* __restrict__ sums, float* __restrict__ sumsq)
{
    const int b = blockIdx.x / STATS_SPLIT;
    const int part = blockIdx.x % STATS_SPLIT;
    const int tid = threadIdx.x;
    const int start = cums[b], end = cums[b + 1];
    float s = 0.f, s2 = 0.f;
    for (int node = start + part; node < end; node += STATS_SPLIT) {
        const float v = x[(long long)node * 128 + tid];
        s += v;
        s2 += v * v;
    }
    atomicAdd(&sums[b * 128 + tid], s);
    atomicAdd(&sumsq[b * 128 + tid], s2);
}

__global__ __launch_bounds__(128) void finalize_stats_kernel(
    const int* __restrict__ cums, float* __restrict__ sums,
    float* __restrict__ sumsq)
{
    const int b = blockIdx.x;
    const int tid = threadIdx.x;
    const float cnt = (float)(cums[b + 1] - cums[b]);
    const float s = sums[b * 128 + tid];
    const float s2 = sumsq[b * 128 + tid];
    const float mean = s / cnt;
    float var = (s2 - s * mean) / (cnt - 1.f);
    var = fmaxf(var, 0.f);
    sums[b * 128 + tid] = mean;
    sumsq[b * 128 + tid] = 1.f / (sqrtf(var) + 1e-5f);
}

__global__ __launch_bounds__(256) void norm_kernel(
    const float* __restrict__ x, const float* __restrict__ mean,
    const float* __restrict__ istd, const int* __restrict__ cums, int nb,
    const float* __restrict__ gamma, const float* __restrict__ beta,
    float* __restrict__ out, int n)
{
    const long long gid = (long long)blockIdx.x * 256 + threadIdx.x;
    const int node = (int)(gid >> 5);
    if (node >= n) return;
    const int f4 = (int)(gid & 31);
    int lo = 0, hi = nb;
    while (hi - lo > 1) {
        const int mid = (lo + hi) >> 1;
        if (cums[mid] <= node) lo = mid; else hi = mid;
    }
    const float4 m = *(const float4*)&mean[lo * 128 + f4 * 4];
    const float4 is = *(const float4*)&istd[lo * 128 + f4 * 4];
    const float4 g = *(const float4*)&gamma[f4 * 4];
    const float4 bt = *(const float4*)&beta[f4 * 4];
    const float4 v = *(const float4*)&x[(long long)node * 128 + f4 * 4];
    float4 o;
    o.x = g.x * ((v.x - m.x) * is.x) + bt.x;
    o.y = g.y * ((v.y - m.y) * is.y) + bt.y;
    o.z = g.z * ((v.z - m.z) * is.z) + bt.z;
    o.w = g.w * ((v.w - m.w) * is.w) + bt.w;
    *(float4*)&out[(long long)node * 128 + f4 * 4] = o;
}

// ---------------------------------------------------------------------------
extern "C" void kernel_launch(void* const* d_in, const int* in_sizes, int n_in,
                              void* d_out, int out_size, void* d_ws, size_t ws_size,
                              hipStream_t stream) {
    const float* input   = (const float*)d_in[0];
    const float* h0      = (const float*)d_in[1];
    const int*   src     = (const int*)d_in[2];
    const int*   dst     = (const int*)d_in[3];
    const int*   cums    = (const int*)d_in[4];
    const int*   l_p     = (const int*)d_in[5];
    const float* lamda_p = (const float*)d_in[6];
    const float* alpha_p = (const float*)d_in[7];
    const float* W_fc    = (const float*)d_in[8];
    const float* attn_l  = (const float*)d_in[9];
    const float* attn_r  = (const float*)d_in[10];
    const float* gat_bias= (const float*)d_in[11];
    const float* W_comb  = (const float*)d_in[12];
    const float* gamma   = (const float*)d_in[13];
    const float* beta    = (const float*)d_in[14];

    const int n  = in_sizes[0] / 128;
    const int E  = in_sizes[2];
    const int nb = in_sizes[4] - 1;
    float* out = (float*)d_out;

    // workspace layout
    char* ws = (char*)d_ws;
    size_t o = 0;
    unsigned short* h = (unsigned short*)(ws + o); o += (size_t)n * 128 * 2;
    float* el       = (float*)(ws + o); o += (size_t)n * 8 * 4;
    float* er       = (float*)(ws + o); o += (size_t)n * 8 * 4;
    float* rst      = (float*)(ws + o); o += (size_t)n * 128 * 4;
    float* sums     = (float*)(ws + o); o += (size_t)nb * 128 * 4;
    float* sumsq    = (float*)(ws + o); o += (size_t)nb * 128 * 4;
    int* deg        = (int*)(ws + o);   o += (size_t)n * 4;
    int* row_ptr    = (int*)(ws + o);   o += (size_t)(n + 1) * 4;
    int* cursor     = (int*)(ws + o);   o += (size_t)n * 4;
    int* blockSums  = (int*)(ws + o);   o += 128 * 4;
    int* srcs       = (int*)(ws + o);   o += (size_t)E * 4;

    hipMemsetAsync(deg, 0, (size_t)n * 4, stream);
    hipMemsetAsync(sums, 0, (size_t)nb * 128 * 4 * 2, stream);

    // --- CSR build ---
    hist_kernel<<<(E + 255) / 256, 256, 0, stream>>>(dst, deg, E);
    const int nblk1 = (n + 1023) / 1024;
    scan1_kernel<<<nblk1, 256, 0, stream>>>(deg, row_ptr, blockSums, n);
    scan2_kernel<<<1, 128, 0, stream>>>(blockSums, nblk1);
    scan3_kernel<<<(n + 255) / 256, 256, 0, stream>>>(row_ptr, cursor, blockSums, n, E);
    scatter_kernel<<<(E + 255) / 256, 256, 0, stream>>>(src, dst, cursor, srcs, E);

    // --- dense pipeline ---
    const int gemm_grid = (n + 63) / 64;
    fc_gemm_kernel<<<gemm_grid, 256, 0, stream>>>(
        input, W_fc, attn_l, attn_r, h, el, er, n);

    aggregate_kernel<<<(n + 3) / 4, 256, 0, stream>>>(
        el, er, h, row_ptr, srcs, rst, n);

    combine_gemm_kernel<<<gemm_grid, 256, 0, stream>>>(
        rst, gat_bias, h0, input, W_comb, l_p, lamda_p, alpha_p, out, n);

    stats_kernel<<<nb * STATS_SPLIT, 128, 0, stream>>>(out, cums, sums, sumsq);
    finalize_stats_kernel<<<nb, 128, 0, stream>>>(cums, sums, sumsq);

    const long long norm_threads = (long long)n * 32;
    norm_kernel<<<(int)((norm_threads + 255) / 256), 256, 0, stream>>>(
        out, sums, sumsq, cums, nb, gamma, beta, out, n);
}

// Round 9
// 311.487 us; speedup vs baseline: 1.2708x; 1.0985x over previous
//
#include <hip/hip_runtime.h>
#include <hip/hip_bf16.h>

#define NEG_SLOPE 0.2f
#define STATS_SPLIT 50

typedef short bf16x8 __attribute__((ext_vector_type(8)));
typedef float f32x4 __attribute__((ext_vector_type(4)));

__device__ __forceinline__ unsigned short f2bf(float f) {
    unsigned int u = __float_as_uint(f);
    unsigned int r = (u + 0x7fffu + ((u >> 16) & 1u)) >> 16;
    return (unsigned short)r;
}
__device__ __forceinline__ float bf2f(unsigned short h) {
    return __uint_as_float(((unsigned int)h) << 16);
}

// ---------------------------------------------------------------------------
// K0: prep. Wt_fc[144][128] bf16 = [W_fc^T ; (W_fc@attn_l)^T ; (W_fc@attn_r)^T]
// (el/er become GEMM columns 128..143: (x@W)·attn == x@(W@attn), exact).
// Wt_cb[128][256] bf16 = W_comb^T.
// ---------------------------------------------------------------------------
__global__ __launch_bounds__(256) void prep_kernel(
    const float* __restrict__ W_fc, const float* __restrict__ attn_l,
    const float* __restrict__ attn_r, const float* __restrict__ W_comb,
    unsigned short* __restrict__ Wt_fc, unsigned short* __restrict__ Wt_cb)
{
    const int t = blockIdx.x * 256 + threadIdx.x;
    const int stride = gridDim.x * 256;
    for (int i = t; i < 128 * 128; i += stride) {
        const int c = i >> 7, k = i & 127;
        Wt_fc[c * 128 + k] = f2bf(W_fc[k * 128 + c]);
    }
    for (int i = t; i < 8 * 128; i += stride) {
        const int hd = i >> 7, k = i & 127;
        float sl = 0.f, sr = 0.f;
        for (int d = 0; d < 16; ++d) {
            const float w = W_fc[k * 128 + hd * 16 + d];
            sl += w * attn_l[hd * 16 + d];
            sr += w * attn_r[hd * 16 + d];
        }
        Wt_fc[(128 + hd) * 128 + k] = f2bf(sl);
        Wt_fc[(136 + hd) * 128 + k] = f2bf(sr);
    }
    for (int i = t; i < 128 * 256; i += stride) {
        const int c = i >> 8, k = i & 255;
        Wt_cb[c * 256 + k] = f2bf(W_comb[k * 128 + c]);
    }
}

// ---------------------------------------------------------------------------
// K1: h = input @ W_fc via bf16 MFMA, el/er as extra output columns.
// 64-row tile, 4 waves; wave w -> rows w*16..+15, 9 col-tiles (8 h + 1 el/er).
// Frag maps (guide §3): A/B elem=(lane&15, (lane>>4)*8+i); D col=lane&15,
// row=(lane>>4)*4+reg. LDS pad 40 bf16/row -> 2-way (free) frag reads.
// ---------------------------------------------------------------------------
__global__ __launch_bounds__(256) void fc_gemm_kernel(
    const float* __restrict__ A, const unsigned short* __restrict__ Wt,
    unsigned short* __restrict__ h, float* __restrict__ el,
    float* __restrict__ er, int n)
{
    __shared__ unsigned short As[64][40];
    __shared__ unsigned short Bs[144][40];
    const int tid = threadIdx.x;
    const int wave = tid >> 6;
    const int lane = tid & 63;
    const int m16 = lane & 15;
    const int kg = lane >> 4;
    const int rowBase = blockIdx.x * 64;

    f32x4 acc[9];
#pragma unroll
    for (int t = 0; t < 9; ++t) acc[t] = (f32x4){0.f, 0.f, 0.f, 0.f};

    const int rS = tid >> 2;      // A-stage row 0..63
    const int pS = tid & 3;       // A-stage 8-elem part

    for (int ci = 0; ci < 4; ++ci) {
        const int kc = ci * 32;
        if (ci) __syncthreads();
        // stage A: 64 rows x 32 k, f32 -> bf16
        {
            int row = rowBase + rS;
            if (row >= n) row = n - 1;
            const float4 v0 = *(const float4*)&A[(long long)row * 128 + kc + pS * 8];
            const float4 v1 = *(const float4*)&A[(long long)row * 128 + kc + pS * 8 + 4];
            bf16x8 pk;
            pk[0] = (short)f2bf(v0.x); pk[1] = (short)f2bf(v0.y);
            pk[2] = (short)f2bf(v0.z); pk[3] = (short)f2bf(v0.w);
            pk[4] = (short)f2bf(v1.x); pk[5] = (short)f2bf(v1.y);
            pk[6] = (short)f2bf(v1.z); pk[7] = (short)f2bf(v1.w);
            *(bf16x8*)&As[rS][pS * 8] = pk;
        }
        // stage B: 144 rows x 32 k from Wt (bf16, coalesced 16B)
        for (int i = tid; i < 576; i += 256) {
            const int r = i >> 2, p = i & 3;
            *(bf16x8*)&Bs[r][p * 8] =
                *(const bf16x8*)&Wt[r * 128 + kc + p * 8];
        }
        __syncthreads();

        const bf16x8 afrag = *(const bf16x8*)&As[wave * 16 + m16][kg * 8];
#pragma unroll
        for (int t = 0; t < 9; ++t) {
            const bf16x8 bfrag = *(const bf16x8*)&Bs[t * 16 + m16][kg * 8];
            acc[t] = __builtin_amdgcn_mfma_f32_16x16x32_bf16(afrag, bfrag, acc[t], 0, 0, 0);
        }
    }

    // epilogue: h (bf16) from tiles 0-7; el/er from tile 8.
    const int r0 = rowBase + wave * 16 + kg * 4;
#pragma unroll
    for (int t = 0; t < 8; ++t) {
#pragma unroll
        for (int j = 0; j < 4; ++j) {
            const int row = r0 + j;
            if (row < n)
                h[(long long)row * 128 + t * 16 + m16] = f2bf(acc[t][j]);
        }
    }
#pragma unroll
    for (int j = 0; j < 4; ++j) {
        const int row = r0 + j;
        if (row < n) {
            const float v = acc[8][j];
            if (m16 < 8) el[(long long)row * 8 + m16] = v;
            else         er[(long long)row * 8 + (m16 - 8)] = v;
        }
    }
}

// ---------------------------------------------------------------------------
// CSR build: histogram -> 2-level exclusive scan -> scatter src ids by dst.
// ---------------------------------------------------------------------------
__global__ __launch_bounds__(256) void hist_kernel(
    const int* __restrict__ dst, int* __restrict__ deg, int E)
{
    const int i = blockIdx.x * 256 + threadIdx.x;
    if (i < E) atomicAdd(&deg[dst[i]], 1);
}

__global__ __launch_bounds__(256) void scan1_kernel(
    const int* __restrict__ deg, int* __restrict__ row,
    int* __restrict__ blockSums, int n)
{
    __shared__ int sdata[256];
    const int t = threadIdx.x;
    const int base = blockIdx.x * 1024 + t * 4;
    int v[4];
    int tot = 0;
#pragma unroll
    for (int j = 0; j < 4; ++j) {
        v[j] = (base + j < n) ? deg[base + j] : 0;
        tot += v[j];
    }
    sdata[t] = tot;
    __syncthreads();
    for (int off = 1; off < 256; off <<= 1) {
        const int x = (t >= off) ? sdata[t - off] : 0;
        __syncthreads();
        sdata[t] += x;
        __syncthreads();
    }
    if (t == 255) blockSums[blockIdx.x] = sdata[255];
    int run = sdata[t] - tot;
#pragma unroll
    for (int j = 0; j < 4; ++j) {
        if (base + j < n) row[base + j] = run;
        run += v[j];
    }
}

__global__ __launch_bounds__(128) void scan2_kernel(
    int* __restrict__ blockSums, int nb)
{
    __shared__ int sdata[128];
    const int t = threadIdx.x;
    const int v = (t < nb) ? blockSums[t] : 0;
    sdata[t] = v;
    __syncthreads();
    for (int off = 1; off < 128; off <<= 1) {
        const int x = (t >= off) ? sdata[t - off] : 0;
        __syncthreads();
        sdata[t] += x;
        __syncthreads();
    }
    if (t < nb) blockSums[t] = sdata[t] - v;
}

__global__ __launch_bounds__(256) void scan3_kernel(
    int* __restrict__ row, int* __restrict__ cursor,
    const int* __restrict__ blockSums, int n, int E)
{
    const int i = blockIdx.x * 256 + threadIdx.x;
    if (i == 0) row[n] = E;
    if (i >= n) return;
    const int r = row[i] + blockSums[i >> 10];
    row[i] = r;
    cursor[i] = r;
}

__global__ __launch_bounds__(256) void scatter_kernel(
    const int* __restrict__ src, const int* __restrict__ dst,
    int* __restrict__ cursor, int* __restrict__ srcs, int E)
{
    const int i = blockIdx.x * 256 + threadIdx.x;
    if (i >= E) return;
    const int pos = atomicAdd(&cursor[dst[i]], 1);
    srcs[pos] = src[i];
}

// ---------------------------------------------------------------------------
// K3: aggregate. One wave per dst node, 2 features/lane, local softmax,
// no atomics. h gathered as bf16.
// ---------------------------------------------------------------------------
__global__ __launch_bounds__(256) void aggregate_kernel(
    const float* __restrict__ el, const float* __restrict__ er,
    const unsigned short* __restrict__ h, const int* __restrict__ row,
    const int* __restrict__ srcs, float* __restrict__ rst, int n)
{
    const int wave = blockIdx.x * 4 + (threadIdx.x >> 6);
    const int lane = threadIdx.x & 63;
    if (wave >= n) return;
    const int d = wave;
    const int start = row[d], end = row[d + 1];
    const int hd0 = lane >> 4;
    const float er0 = er[(long long)d * 8 + hd0];
    const float er1 = er[(long long)d * 8 + hd0 + 4];

    float acc0 = 0.f, acc1 = 0.f, den0 = 0.f, den1 = 0.f;
    for (int p = start; p < end; ++p) {
        const int s = srcs[p];
        float e0 = el[(long long)s * 8 + hd0] + er0;
        float e1 = el[(long long)s * 8 + hd0 + 4] + er1;
        e0 = e0 >= 0.f ? e0 : NEG_SLOPE * e0;
        e1 = e1 >= 0.f ? e1 : NEG_SLOPE * e1;
        const float w0 = __expf(e0);
        const float w1 = __expf(e1);
        den0 += w0; den1 += w1;
        acc0 += w0 * bf2f(h[(long long)s * 128 + lane]);
        acc1 += w1 * bf2f(h[(long long)s * 128 + 64 + lane]);
    }
    const float r0 = (end > start) ? acc0 / den0 : 0.f;
    const float r1 = (end > start) ? acc1 / den1 : 0.f;
    rst[(long long)d * 128 + lane] = r0;
    rst[(long long)d * 128 + 64 + lane] = r1;
}

// ---------------------------------------------------------------------------
// K4: GCNII combine via bf16 MFMA. K=256 (rst+bias chunks 0-3, h0 chunks
// 4-7). Epilogue: theta*acc + c1*(rst+bias) + c2*h0 + input (scalar, L2-warm).
// ---------------------------------------------------------------------------
__global__ __launch_bounds__(256) void combine_gemm_kernel(
    const float* __restrict__ rst, const float* __restrict__ gat_bias,
    const float* __restrict__ h0, const float* __restrict__ input,
    const unsigned short* __restrict__ Wt, const int* __restrict__ l_p,
    const float* __restrict__ lamda_p, const float* __restrict__ alpha_p,
    float* __restrict__ x, int n)
{
    __shared__ unsigned short As[64][40];
    __shared__ unsigned short Bs[128][40];
    const int tid = threadIdx.x;
    const int wave = tid >> 6;
    const int lane = tid & 63;
    const int m16 = lane & 15;
    const int kg = lane >> 4;
    const int rowBase = blockIdx.x * 64;

    f32x4 acc[8];
#pragma unroll
    for (int t = 0; t < 8; ++t) acc[t] = (f32x4){0.f, 0.f, 0.f, 0.f};

    const int rS = tid >> 2;
    const int pS = tid & 3;

    for (int ci = 0; ci < 8; ++ci) {
        const int kc = ci * 32;
        const int koff = kc & 127;
        const bool first = ci < 4;
        if (ci) __syncthreads();
        // stage A: rst+bias (chunks 0-3) or h0 (chunks 4-7), f32 -> bf16
        {
            int row = rowBase + rS;
            if (row >= n) row = n - 1;
            float4 v0, v1;
            if (first) {
                v0 = *(const float4*)&rst[(long long)row * 128 + koff + pS * 8];
                v1 = *(const float4*)&rst[(long long)row * 128 + koff + pS * 8 + 4];
                const float4 b0 = *(const float4*)&gat_bias[koff + pS * 8];
                const float4 b1 = *(const float4*)&gat_bias[koff + pS * 8 + 4];
                v0.x += b0.x; v0.y += b0.y; v0.z += b0.z; v0.w += b0.w;
                v1.x += b1.x; v1.y += b1.y; v1.z += b1.z; v1.w += b1.w;
            } else {
                v0 = *(const float4*)&h0[(long long)row * 128 + koff + pS * 8];
                v1 = *(const float4*)&h0[(long long)row * 128 + koff + pS * 8 + 4];
            }
            bf16x8 pk;
            pk[0] = (short)f2bf(v0.x); pk[1] = (short)f2bf(v0.y);
            pk[2] = (short)f2bf(v0.z); pk[3] = (short)f2bf(v0.w);
            pk[4] = (short)f2bf(v1.x); pk[5] = (short)f2bf(v1.y);
            pk[6] = (short)f2bf(v1.z); pk[7] = (short)f2bf(v1.w);
            *(bf16x8*)&As[rS][pS * 8] = pk;
        }
        // stage B: 128 rows x 32 k from Wt_cb
        for (int i = tid; i < 512; i += 256) {
            const int r = i >> 2, p = i & 3;
            *(bf16x8*)&Bs[r][p * 8] =
                *(const bf16x8*)&Wt[r * 256 + kc + p * 8];
        }
        __syncthreads();

        const bf16x8 afrag = *(const bf16x8*)&As[wave * 16 + m16][kg * 8];
#pragma unroll
        for (int t = 0; t < 8; ++t) {
            const bf16x8 bfrag = *(const bf16x8*)&Bs[t * 16 + m16][kg * 8];
            acc[t] = __builtin_amdgcn_mfma_f32_16x16x32_bf16(afrag, bfrag, acc[t], 0, 0, 0);
        }
    }

    const float alpha = alpha_p[0];
    const float theta = fminf(1.0f, logf(lamda_p[0] / (float)l_p[0] + 1.0f));
    const float c1 = (1.f - theta) * (1.f - alpha);
    const float c2 = (1.f - theta) * alpha;
    const int r0 = rowBase + wave * 16 + kg * 4;

#pragma unroll
    for (int t = 0; t < 8; ++t) {
        const int col = t * 16 + m16;
        const float bias = gat_bias[col];
#pragma unroll
        for (int j = 0; j < 4; ++j) {
            const int row = r0 + j;
            if (row < n) {
                const long long off = (long long)row * 128 + col;
                x[off] = theta * acc[t][j] + c1 * (rst[off] + bias)
                       + c2 * h0[off] + input[off];
            }
        }
    }
}

// ---------------------------------------------------------------------------
// K5: per-subgraph partial sums (split over nodes, atomics into (B,128)).
// ---------------------------------------------------------------------------
__global__ __launch_bounds__(128) void stats_kernel(
    const float* __restrict__ x, const int* __restrict__ cums,
    float* __restrict__ sums, float* __restrict__ sumsq)
{
    const int b = blockIdx.x / STATS_SPLIT;
    const int part = blockIdx.x % STATS_SPLIT;
    const int tid = threadIdx.x;
    const int start = cums[b], end = cums[b + 1];
    float s = 0.f, s2 = 0.f;
    for (int node = start + part; node < end; node += STATS_SPLIT) {
        const float v = x[(long long)node * 128 + tid];
        s += v;
        s2 += v * v;
    }
    atomicAdd(&sums[b * 128 + tid], s);
    atomicAdd(&sumsq[b * 128 + tid], s2);
}

__global__ __launch_bounds__(128) void finalize_stats_kernel(
    const int* __restrict__ cums, float* __restrict__ sums,
    float* __restrict__ sumsq)
{
    const int b = blockIdx.x;
    const int tid = threadIdx.x;
    const float cnt = (float)(cums[b + 1] - cums[b]);
    const float s = sums[b * 128 + tid];
    const float s2 = sumsq[b * 128 + tid];
    const float mean = s / cnt;
    float var = (s2 - s * mean) / (cnt - 1.f);
    var = fmaxf(var, 0.f);
    sums[b * 128 + tid] = mean;
    sumsq[b * 128 + tid] = 1.f / (sqrtf(var) + 1e-5f);
}

__global__ __launch_bounds__(256) void norm_kernel(
    const float* __restrict__ x, const float* __restrict__ mean,
    const float* __restrict__ istd, const int* __restrict__ cums, int nb,
    const float* __restrict__ gamma, const float* __restrict__ beta,
    float* __restrict__ out, int n)
{
    const long long gid = (long long)blockIdx.x * 256 + threadIdx.x;
    const int node = (int)(gid >> 5);
    if (node >= n) return;
    const int f4 = (int)(gid & 31);
    int lo = 0, hi = nb;
    while (hi - lo > 1) {
        const int mid = (lo + hi) >> 1;
        if (cums[mid] <= node) lo = mid; else hi = mid;
    }
    const float4 m = *(const float4*)&mean[lo * 128 + f4 * 4];
    const float4 is = *(const float4*)&istd[lo * 128 + f4 * 4];
    const float4 g = *(const float4*)&gamma[f4 * 4];
    const float4 bt = *(const float4*)&beta[f4 * 4];
    const float4 v = *(const float4*)&x[(long long)node * 128 + f4 * 4];
    float4 o;
    o.x = g.x * ((v.x - m.x) * is.x) + bt.x;
    o.y = g.y * ((v.y - m.y) * is.y) + bt.y;
    o.z = g.z * ((v.z - m.z) * is.z) + bt.z;
    o.w = g.w * ((v.w - m.w) * is.w) + bt.w;
    *(float4*)&out[(long long)node * 128 + f4 * 4] = o;
}

// ---------------------------------------------------------------------------
extern "C" void kernel_launch(void* const* d_in, const int* in_sizes, int n_in,
                              void* d_out, int out_size, void* d_ws, size_t ws_size,
                              hipStream_t stream) {
    const float* input   = (const float*)d_in[0];
    const float* h0      = (const float*)d_in[1];
    const int*   src     = (const int*)d_in[2];
    const int*   dst     = (const int*)d_in[3];
    const int*   cums    = (const int*)d_in[4];
    const int*   l_p     = (const int*)d_in[5];
    const float* lamda_p = (const float*)d_in[6];
    const float* alpha_p = (const float*)d_in[7];
    const float* W_fc    = (const float*)d_in[8];
    const float* attn_l  = (const float*)d_in[9];
    const float* attn_r  = (const float*)d_in[10];
    const float* gat_bias= (const float*)d_in[11];
    const float* W_comb  = (const float*)d_in[12];
    const float* gamma   = (const float*)d_in[13];
    const float* beta    = (const float*)d_in[14];

    const int n  = in_sizes[0] / 128;
    const int E  = in_sizes[2];
    const int nb = in_sizes[4] - 1;
    float* out = (float*)d_out;

    // workspace layout (all offsets 16B-aligned)
    char* ws = (char*)d_ws;
    size_t o = 0;
#define ALLOC(ptr, type, count)                                              \
    type* ptr = (type*)(ws + o); o = (o + (size_t)(count) * sizeof(type) + 15) & ~(size_t)15;
    ALLOC(h,        unsigned short, (size_t)n * 128)
    ALLOC(el,       float,          (size_t)n * 8)
    ALLOC(er,       float,          (size_t)n * 8)
    ALLOC(rst,      float,          (size_t)n * 128)
    ALLOC(sums,     float,          (size_t)nb * 128)
    ALLOC(sumsq,    float,          (size_t)nb * 128)
    ALLOC(deg,      int,            (size_t)n)
    ALLOC(row_ptr,  int,            (size_t)n + 1)
    ALLOC(cursor,   int,            (size_t)n)
    ALLOC(blockSums,int,            128)
    ALLOC(srcs,     int,            (size_t)E)
    ALLOC(Wt_fc,    unsigned short, 144 * 128)
    ALLOC(Wt_cb,    unsigned short, 128 * 256)
#undef ALLOC

    hipMemsetAsync(deg, 0, (size_t)n * 4, stream);
    hipMemsetAsync(sums, 0, (size_t)nb * 128 * 4, stream);
    hipMemsetAsync(sumsq, 0, (size_t)nb * 128 * 4, stream);

    // --- prep (weights -> bf16 transposed, fused attn columns) ---
    prep_kernel<<<64, 256, 0, stream>>>(W_fc, attn_l, attn_r, W_comb, Wt_fc, Wt_cb);

    // --- CSR build ---
    hist_kernel<<<(E + 255) / 256, 256, 0, stream>>>(dst, deg, E);
    const int nblk1 = (n + 1023) / 1024;
    scan1_kernel<<<nblk1, 256, 0, stream>>>(deg, row_ptr, blockSums, n);
    scan2_kernel<<<1, 128, 0, stream>>>(blockSums, nblk1);
    scan3_kernel<<<(n + 255) / 256, 256, 0, stream>>>(row_ptr, cursor, blockSums, n, E);
    scatter_kernel<<<(E + 255) / 256, 256, 0, stream>>>(src, dst, cursor, srcs, E);

    // --- dense pipeline ---
    const int gemm_grid = (n + 63) / 64;
    fc_gemm_kernel<<<gemm_grid, 256, 0, stream>>>(input, Wt_fc, h, el, er, n);

    aggregate_kernel<<<(n + 3) / 4, 256, 0, stream>>>(
        el, er, h, row_ptr, srcs, rst, n);

    combine_gemm_kernel<<<gemm_grid, 256, 0, stream>>>(
        rst, gat_bias, h0, input, Wt_cb, l_p, lamda_p, alpha_p, out, n);

    stats_kernel<<<nb * STATS_SPLIT, 128, 0, stream>>>(out, cums, sums, sumsq);
    finalize_stats_kernel<<<nb, 128, 0, stream>>>(cums, sums, sumsq);

    const long long norm_threads = (long long)n * 32;
    norm_kernel<<<(int)((norm_threads + 255) / 256), 256, 0, stream>>>(
        out, sums, sumsq, cums, nb, gamma, beta, out, n);
}

// Round 10
// 270.410 us; speedup vs baseline: 1.4639x; 1.1519x over previous
//
#include <hip/hip_runtime.h>
#include <hip/hip_bf16.h>

#define NEG_SLOPE 0.2f
#define STATS_SPLIT 50

typedef short bf16x8 __attribute__((ext_vector_type(8)));
typedef float f32x4 __attribute__((ext_vector_type(4)));

__device__ __forceinline__ unsigned short f2bf(float f) {
    unsigned int u = __float_as_uint(f);
    unsigned int r = (u + 0x7fffu + ((u >> 16) & 1u)) >> 16;
    return (unsigned short)r;
}
__device__ __forceinline__ float bf2f(unsigned short h) {
    return __uint_as_float(((unsigned int)h) << 16);
}

// ---------------------------------------------------------------------------
// K0: prep.
// Wt_fc[144][128] bf16 = [W_fc^T ; (W_fc@attn_l)^T ; (W_fc@attn_r)^T].
// Wt_cb[128][256] bf16 = theta*W_comb^T + c1*delta(k==c) + c2*delta(k==c+128)
//   -- folds the GCNII linear blend INTO the GEMM (exact algebra), so the
//   combine epilogue is just acc + input.
// ---------------------------------------------------------------------------
__global__ __launch_bounds__(256) void prep_kernel(
    const float* __restrict__ W_fc, const float* __restrict__ attn_l,
    const float* __restrict__ attn_r, const float* __restrict__ W_comb,
    const int* __restrict__ l_p, const float* __restrict__ lamda_p,
    const float* __restrict__ alpha_p,
    unsigned short* __restrict__ Wt_fc, unsigned short* __restrict__ Wt_cb)
{
    const float alpha = alpha_p[0];
    const float theta = fminf(1.0f, logf(lamda_p[0] / (float)l_p[0] + 1.0f));
    const float c1 = (1.f - theta) * (1.f - alpha);
    const float c2 = (1.f - theta) * alpha;

    const int t = blockIdx.x * 256 + threadIdx.x;
    const int stride = gridDim.x * 256;
    for (int i = t; i < 128 * 128; i += stride) {
        const int c = i >> 7, k = i & 127;
        Wt_fc[c * 128 + k] = f2bf(W_fc[k * 128 + c]);
    }
    for (int i = t; i < 8 * 128; i += stride) {
        const int hd = i >> 7, k = i & 127;
        float sl = 0.f, sr = 0.f;
        for (int d = 0; d < 16; ++d) {
            const float w = W_fc[k * 128 + hd * 16 + d];
            sl += w * attn_l[hd * 16 + d];
            sr += w * attn_r[hd * 16 + d];
        }
        Wt_fc[(128 + hd) * 128 + k] = f2bf(sl);
        Wt_fc[(136 + hd) * 128 + k] = f2bf(sr);
    }
    for (int i = t; i < 128 * 256; i += stride) {
        const int c = i >> 8, k = i & 255;
        float w = theta * W_comb[k * 128 + c];
        if (k == c) w += c1;
        if (k == c + 128) w += c2;
        Wt_cb[c * 256 + k] = f2bf(w);
    }
}

// ---------------------------------------------------------------------------
// K1: h = input @ W_fc via bf16 MFMA, el/er as extra output columns.
// 64-row tile, 4 waves, 9 col-tiles. Pad 36 (18-bank row stride): the 16
// fragment rows map to 16 distinct banks -> conflict-free ds_read_b128.
// ---------------------------------------------------------------------------
__global__ __launch_bounds__(256) void fc_gemm_kernel(
    const float* __restrict__ A, const unsigned short* __restrict__ Wt,
    unsigned short* __restrict__ h, float* __restrict__ el,
    float* __restrict__ er, int n)
{
    __shared__ unsigned short As[64][36];
    __shared__ unsigned short Bs[144][36];
    const int tid = threadIdx.x;
    const int wave = tid >> 6;
    const int lane = tid & 63;
    const int m16 = lane & 15;
    const int kg = lane >> 4;
    const int rowBase = blockIdx.x * 64;

    f32x4 acc[9];
#pragma unroll
    for (int t = 0; t < 9; ++t) acc[t] = (f32x4){0.f, 0.f, 0.f, 0.f};

    const int rS = tid >> 2;
    const int pS = tid & 3;

    for (int ci = 0; ci < 4; ++ci) {
        const int kc = ci * 32;
        if (ci) __syncthreads();
        {
            int row = rowBase + rS;
            if (row >= n) row = n - 1;
            const float4 v0 = *(const float4*)&A[(long long)row * 128 + kc + pS * 8];
            const float4 v1 = *(const float4*)&A[(long long)row * 128 + kc + pS * 8 + 4];
            bf16x8 pk;
            pk[0] = (short)f2bf(v0.x); pk[1] = (short)f2bf(v0.y);
            pk[2] = (short)f2bf(v0.z); pk[3] = (short)f2bf(v0.w);
            pk[4] = (short)f2bf(v1.x); pk[5] = (short)f2bf(v1.y);
            pk[6] = (short)f2bf(v1.z); pk[7] = (short)f2bf(v1.w);
            *(bf16x8*)&As[rS][pS * 8] = pk;
        }
        for (int i = tid; i < 576; i += 256) {
            const int r = i >> 2, p = i & 3;
            *(bf16x8*)&Bs[r][p * 8] =
                *(const bf16x8*)&Wt[r * 128 + kc + p * 8];
        }
        __syncthreads();

        const bf16x8 afrag = *(const bf16x8*)&As[wave * 16 + m16][kg * 8];
#pragma unroll
        for (int t = 0; t < 9; ++t) {
            const bf16x8 bfrag = *(const bf16x8*)&Bs[t * 16 + m16][kg * 8];
            acc[t] = __builtin_amdgcn_mfma_f32_16x16x32_bf16(afrag, bfrag, acc[t], 0, 0, 0);
        }
    }

    const int r0 = rowBase + wave * 16 + kg * 4;
#pragma unroll
    for (int t = 0; t < 8; ++t) {
#pragma unroll
        for (int j = 0; j < 4; ++j) {
            const int row = r0 + j;
            if (row < n)
                h[(long long)row * 128 + t * 16 + m16] = f2bf(acc[t][j]);
        }
    }
#pragma unroll
    for (int j = 0; j < 4; ++j) {
        const int row = r0 + j;
        if (row < n) {
            const float v = acc[8][j];
            if (m16 < 8) el[(long long)row * 8 + m16] = v;
            else         er[(long long)row * 8 + (m16 - 8)] = v;
        }
    }
}

// ---------------------------------------------------------------------------
// CSR build: histogram -> 2-level exclusive scan -> scatter src ids by dst.
// ---------------------------------------------------------------------------
__global__ __launch_bounds__(256) void hist_kernel(
    const int* __restrict__ dst, int* __restrict__ deg, int E)
{
    const int i = blockIdx.x * 256 + threadIdx.x;
    if (i < E) atomicAdd(&deg[dst[i]], 1);
}

__global__ __launch_bounds__(256) void scan1_kernel(
    const int* __restrict__ deg, int* __restrict__ row,
    int* __restrict__ blockSums, int n)
{
    __shared__ int sdata[256];
    const int t = threadIdx.x;
    const int base = blockIdx.x * 1024 + t * 4;
    int v[4];
    int tot = 0;
#pragma unroll
    for (int j = 0; j < 4; ++j) {
        v[j] = (base + j < n) ? deg[base + j] : 0;
        tot += v[j];
    }
    sdata[t] = tot;
    __syncthreads();
    for (int off = 1; off < 256; off <<= 1) {
        const int x = (t >= off) ? sdata[t - off] : 0;
        __syncthreads();
        sdata[t] += x;
        __syncthreads();
    }
    if (t == 255) blockSums[blockIdx.x] = sdata[255];
    int run = sdata[t] - tot;
#pragma unroll
    for (int j = 0; j < 4; ++j) {
        if (base + j < n) row[base + j] = run;
        run += v[j];
    }
}

__global__ __launch_bounds__(128) void scan2_kernel(
    int* __restrict__ blockSums, int nb)
{
    __shared__ int sdata[128];
    const int t = threadIdx.x;
    const int v = (t < nb) ? blockSums[t] : 0;
    sdata[t] = v;
    __syncthreads();
    for (int off = 1; off < 128; off <<= 1) {
        const int x = (t >= off) ? sdata[t - off] : 0;
        __syncthreads();
        sdata[t] += x;
        __syncthreads();
    }
    if (t < nb) blockSums[t] = sdata[t] - v;
}

__global__ __launch_bounds__(256) void scan3_kernel(
    int* __restrict__ row, int* __restrict__ cursor,
    const int* __restrict__ blockSums, int n, int E)
{
    const int i = blockIdx.x * 256 + threadIdx.x;
    if (i == 0) row[n] = E;
    if (i >= n) return;
    const int r = row[i] + blockSums[i >> 10];
    row[i] = r;
    cursor[i] = r;
}

__global__ __launch_bounds__(256) void scatter_kernel(
    const int* __restrict__ src, const int* __restrict__ dst,
    int* __restrict__ cursor, int* __restrict__ srcs, int E)
{
    const int i = blockIdx.x * 256 + threadIdx.x;
    if (i >= E) return;
    const int pos = atomicAdd(&cursor[dst[i]], 1);
    srcs[pos] = src[i];
}

// ---------------------------------------------------------------------------
// K3: aggregate. One wave per dst node, 2 features/lane, local softmax,
// no atomics. h gathered as bf16.
// ---------------------------------------------------------------------------
__global__ __launch_bounds__(256) void aggregate_kernel(
    const float* __restrict__ el, const float* __restrict__ er,
    const unsigned short* __restrict__ h, const int* __restrict__ row,
    const int* __restrict__ srcs, float* __restrict__ rst, int n)
{
    const int wave = blockIdx.x * 4 + (threadIdx.x >> 6);
    const int lane = threadIdx.x & 63;
    if (wave >= n) return;
    const int d = wave;
    const int start = row[d], end = row[d + 1];
    const int hd0 = lane >> 4;
    const float er0 = er[(long long)d * 8 + hd0];
    const float er1 = er[(long long)d * 8 + hd0 + 4];

    float acc0 = 0.f, acc1 = 0.f, den0 = 0.f, den1 = 0.f;
    for (int p = start; p < end; ++p) {
        const int s = srcs[p];
        float e0 = el[(long long)s * 8 + hd0] + er0;
        float e1 = el[(long long)s * 8 + hd0 + 4] + er1;
        e0 = e0 >= 0.f ? e0 : NEG_SLOPE * e0;
        e1 = e1 >= 0.f ? e1 : NEG_SLOPE * e1;
        const float w0 = __expf(e0);
        const float w1 = __expf(e1);
        den0 += w0; den1 += w1;
        acc0 += w0 * bf2f(h[(long long)s * 128 + lane]);
        acc1 += w1 * bf2f(h[(long long)s * 128 + 64 + lane]);
    }
    const float r0 = (end > start) ? acc0 / den0 : 0.f;
    const float r1 = (end > start) ? acc1 / den1 : 0.f;
    rst[(long long)d * 128 + lane] = r0;
    rst[(long long)d * 128 + 64 + lane] = r1;
}

// ---------------------------------------------------------------------------
// K4: GCNII combine via bf16 MFMA with folded Wmod (prep): out = acc + input.
// Single-barrier double-buffered staging: loads for chunk ci+1 issue BEFORE
// chunk ci's MFMAs (HBM latency hides under compute); cvt+ds_write to the
// alternate buffer after; one barrier per iteration (write targets the
// buffer whose reads were fenced by the previous barrier -> race-free).
// ---------------------------------------------------------------------------
__global__ __launch_bounds__(256) void combine_gemm_kernel(
    const float* __restrict__ rst, const float* __restrict__ gat_bias,
    const float* __restrict__ h0, const float* __restrict__ input,
    const unsigned short* __restrict__ Wt,
    float* __restrict__ x, int n)
{
    __shared__ unsigned short As[2][64][36];
    __shared__ unsigned short Bs[2][128][36];
    const int tid = threadIdx.x;
    const int wave = tid >> 6;
    const int lane = tid & 63;
    const int m16 = lane & 15;
    const int kg = lane >> 4;
    const int rowBase = blockIdx.x * 64;

    f32x4 acc[8];
#pragma unroll
    for (int t = 0; t < 8; ++t) acc[t] = (f32x4){0.f, 0.f, 0.f, 0.f};

    const int rS = tid >> 2;           // A-stage row 0..63
    const int pS = tid & 3;            // A-stage 8-elem part
    const int rB = tid >> 1;           // B-stage row 0..127
    const int p0 = (tid & 1) * 2;      // B-stage parts p0, p0+1

    float4 va0, va1;
    bf16x8 vb0, vb1;
    int arow = rowBase + rS;
    if (arow >= n) arow = n - 1;
    const long long aoff = (long long)arow * 128;

#define CB_LOAD(ci)                                                           \
    {                                                                         \
        const int kc = (ci) * 32;                                             \
        const int koff = kc & 127;                                            \
        if ((ci) < 4) {                                                       \
            va0 = *(const float4*)&rst[aoff + koff + pS * 8];                 \
            va1 = *(const float4*)&rst[aoff + koff + pS * 8 + 4];             \
            const float4 b0 = *(const float4*)&gat_bias[koff + pS * 8];       \
            const float4 b1 = *(const float4*)&gat_bias[koff + pS * 8 + 4];   \
            va0.x += b0.x; va0.y += b0.y; va0.z += b0.z; va0.w += b0.w;       \
            va1.x += b1.x; va1.y += b1.y; va1.z += b1.z; va1.w += b1.w;       \
        } else {                                                              \
            va0 = *(const float4*)&h0[aoff + koff + pS * 8];                  \
            va1 = *(const float4*)&h0[aoff + koff + pS * 8 + 4];              \
        }                                                                     \
        vb0 = *(const bf16x8*)&Wt[rB * 256 + kc + p0 * 8];                    \
        vb1 = *(const bf16x8*)&Wt[rB * 256 + kc + p0 * 8 + 8];                \
    }

#define CB_WRITE(buf)                                                         \
    {                                                                         \
        bf16x8 pk;                                                            \
        pk[0] = (short)f2bf(va0.x); pk[1] = (short)f2bf(va0.y);               \
        pk[2] = (short)f2bf(va0.z); pk[3] = (short)f2bf(va0.w);               \
        pk[4] = (short)f2bf(va1.x); pk[5] = (short)f2bf(va1.y);               \
        pk[6] = (short)f2bf(va1.z); pk[7] = (short)f2bf(va1.w);               \
        *(bf16x8*)&As[buf][rS][pS * 8] = pk;                                  \
        *(bf16x8*)&Bs[buf][rB][p0 * 8] = vb0;                                 \
        *(bf16x8*)&Bs[buf][rB][p0 * 8 + 8] = vb1;                             \
    }

    CB_LOAD(0)
    CB_WRITE(0)
    __syncthreads();

#pragma unroll
    for (int ci = 0; ci < 8; ++ci) {
        const int cur = ci & 1;
        if (ci < 7) CB_LOAD(ci + 1)
        const bf16x8 afrag = *(const bf16x8*)&As[cur][wave * 16 + m16][kg * 8];
#pragma unroll
        for (int t = 0; t < 8; ++t) {
            const bf16x8 bfrag = *(const bf16x8*)&Bs[cur][t * 16 + m16][kg * 8];
            acc[t] = __builtin_amdgcn_mfma_f32_16x16x32_bf16(afrag, bfrag, acc[t], 0, 0, 0);
        }
        if (ci < 7) {
            CB_WRITE(cur ^ 1)
            __syncthreads();
        }
    }
#undef CB_LOAD
#undef CB_WRITE

    const int r0 = rowBase + wave * 16 + kg * 4;
#pragma unroll
    for (int t = 0; t < 8; ++t) {
        const int col = t * 16 + m16;
#pragma unroll
        for (int j = 0; j < 4; ++j) {
            const int row = r0 + j;
            if (row < n) {
                const long long off = (long long)row * 128 + col;
                x[off] = acc[t][j] + input[off];
            }
        }
    }
}

// ---------------------------------------------------------------------------
// K5: per-subgraph partial sums (split over nodes, atomics into (B,128)).
// ---------------------------------------------------------------------------
__global__ __launch_bounds__(128) void stats_kernel(
    const float* __restrict__ x, const int* __restrict__ cums,
    float* __restrict__ sums, float* __restrict__ sumsq)
{
    const int b = blockIdx.x / STATS_SPLIT;
    const int part = blockIdx.x % STATS_SPLIT;
    const int tid = threadIdx.x;
    const int start = cums[b], end = cums[b + 1];
    float s = 0.f, s2 = 0.f;
    for (int node = start + part; node < end; node += STATS_SPLIT) {
        const float v = x[(long long)node * 128 + tid];
        s += v;
        s2 += v * v;
    }
    atomicAdd(&sums[b * 128 + tid], s);
    atomicAdd(&sumsq[b * 128 + tid], s2);
}

__global__ __launch_bounds__(128) void finalize_stats_kernel(
    const int* __restrict__ cums, float* __restrict__ sums,
    float* __restrict__ sumsq)
{
    const int b = blockIdx.x;
    const int tid = threadIdx.x;
    const float cnt = (float)(cums[b + 1] - cums[b]);
    const float s = sums[b * 128 + tid];
    const float s2 = sumsq[b * 128 + tid];
    const float mean = s / cnt;
    float var = (s2 - s * mean) / (cnt - 1.f);
    var = fmaxf(var, 0.f);
    sums[b * 128 + tid] = mean;
    sumsq[b * 128 + tid] = 1.f / (sqrtf(var) + 1e-5f);
}

__global__ __launch_bounds__(256) void norm_kernel(
    const float* __restrict__ x, const float* __restrict__ mean,
    const float* __restrict__ istd, const int* __restrict__ cums, int nb,
    const float* __restrict__ gamma, const float* __restrict__ beta,
    float* __restrict__ out, int n)
{
    const long long gid = (long long)blockIdx.x * 256 + threadIdx.x;
    const int node = (int)(gid >> 5);
    if (node >= n) return;
    const int f4 = (int)(gid & 31);
    int lo = 0, hi = nb;
    while (hi - lo > 1) {
        const int mid = (lo + hi) >> 1;
        if (cums[mid] <= node) lo = mid; else hi = mid;
    }
    const float4 m = *(const float4*)&mean[lo * 128 + f4 * 4];
    const float4 is = *(const float4*)&istd[lo * 128 + f4 * 4];
    const float4 g = *(const float4*)&gamma[f4 * 4];
    const float4 bt = *(const float4*)&beta[f4 * 4];
    const float4 v = *(const float4*)&x[(long long)node * 128 + f4 * 4];
    float4 o;
    o.x = g.x * ((v.x - m.x) * is.x) + bt.x;
    o.y = g.y * ((v.y - m.y) * is.y) + bt.y;
    o.z = g.z * ((v.z - m.z) * is.z) + bt.z;
    o.w = g.w * ((v.w - m.w) * is.w) + bt.w;
    *(float4*)&out[(long long)node * 128 + f4 * 4] = o;
}

// ---------------------------------------------------------------------------
extern "C" void kernel_launch(void* const* d_in, const int* in_sizes, int n_in,
                              void* d_out, int out_size, void* d_ws, size_t ws_size,
                              hipStream_t stream) {
    const float* input   = (const float*)d_in[0];
    const float* h0      = (const float*)d_in[1];
    const int*   src     = (const int*)d_in[2];
    const int*   dst     = (const int*)d_in[3];
    const int*   cums    = (const int*)d_in[4];
    const int*   l_p     = (const int*)d_in[5];
    const float* lamda_p = (const float*)d_in[6];
    const float* alpha_p = (const float*)d_in[7];
    const float* W_fc    = (const float*)d_in[8];
    const float* attn_l  = (const float*)d_in[9];
    const float* attn_r  = (const float*)d_in[10];
    const float* gat_bias= (const float*)d_in[11];
    const float* W_comb  = (const float*)d_in[12];
    const float* gamma   = (const float*)d_in[13];
    const float* beta    = (const float*)d_in[14];

    const int n  = in_sizes[0] / 128;
    const int E  = in_sizes[2];
    const int nb = in_sizes[4] - 1;
    float* out = (float*)d_out;

    // workspace layout (all offsets 16B-aligned)
    char* ws = (char*)d_ws;
    size_t o = 0;
#define ALLOC(ptr, type, count)                                              \
    type* ptr = (type*)(ws + o); o = (o + (size_t)(count) * sizeof(type) + 15) & ~(size_t)15;
    ALLOC(h,        unsigned short, (size_t)n * 128)
    ALLOC(el,       float,          (size_t)n * 8)
    ALLOC(er,       float,          (size_t)n * 8)
    ALLOC(rst,      float,          (size_t)n * 128)
    ALLOC(sums,     float,          (size_t)nb * 128)
    ALLOC(sumsq,    float,          (size_t)nb * 128)
    ALLOC(deg,      int,            (size_t)n)
    ALLOC(row_ptr,  int,            (size_t)n + 1)
    ALLOC(cursor,   int,            (size_t)n)
    ALLOC(blockSums,int,            128)
    ALLOC(srcs,     int,            (size_t)E)
    ALLOC(Wt_fc,    unsigned short, 144 * 128)
    ALLOC(Wt_cb,    unsigned short, 128 * 256)
#undef ALLOC

    hipMemsetAsync(deg, 0, (size_t)n * 4, stream);
    hipMemsetAsync(sums, 0, (size_t)nb * 128 * 4, stream);
    hipMemsetAsync(sumsq, 0, (size_t)nb * 128 * 4, stream);

    // --- prep (weights -> bf16 transposed; attn columns + GCNII fold) ---
    prep_kernel<<<64, 256, 0, stream>>>(
        W_fc, attn_l, attn_r, W_comb, l_p, lamda_p, alpha_p, Wt_fc, Wt_cb);

    // --- CSR build ---
    hist_kernel<<<(E + 255) / 256, 256, 0, stream>>>(dst, deg, E);
    const int nblk1 = (n + 1023) / 1024;
    scan1_kernel<<<nblk1, 256, 0, stream>>>(deg, row_ptr, blockSums, n);
    scan2_kernel<<<1, 128, 0, stream>>>(blockSums, nblk1);
    scan3_kernel<<<(n + 255) / 256, 256, 0, stream>>>(row_ptr, cursor, blockSums, n, E);
    scatter_kernel<<<(E + 255) / 256, 256, 0, stream>>>(src, dst, cursor, srcs, E);

    // --- dense pipeline ---
    const int gemm_grid = (n + 63) / 64;
    fc_gemm_kernel<<<gemm_grid, 256, 0, stream>>>(input, Wt_fc, h, el, er, n);

    aggregate_kernel<<<(n + 3) / 4, 256, 0, stream>>>(
        el, er, h, row_ptr, srcs, rst, n);

    combine_gemm_kernel<<<gemm_grid, 256, 0, stream>>>(
        rst, gat_bias, h0, input, Wt_cb, out, n);

    stats_kernel<<<nb * STATS_SPLIT, 128, 0, stream>>>(out, cums, sums, sumsq);
    finalize_stats_kernel<<<nb, 128, 0, stream>>>(cums, sums, sumsq);

    const long long norm_threads = (long long)n * 32;
    norm_kernel<<<(int)((norm_threads + 255) / 256), 256, 0, stream>>>(
        out, sums, sumsq, cums, nb, gamma, beta, out, n);
}

// Round 11
// 246.494 us; speedup vs baseline: 1.6059x; 1.0970x over previous
//
#include <hip/hip_runtime.h>
#include <hip/hip_bf16.h>

#define NEG_SLOPE 0.2f
#define STATS_SPLIT 50

typedef short bf16x8 __attribute__((ext_vector_type(8)));
typedef float f32x4 __attribute__((ext_vector_type(4)));

__device__ __forceinline__ unsigned short f2bf(float f) {
    unsigned int u = __float_as_uint(f);
    unsigned int r = (u + 0x7fffu + ((u >> 16) & 1u)) >> 16;
    return (unsigned short)r;
}
__device__ __forceinline__ float bf2f(unsigned short h) {
    return __uint_as_float(((unsigned int)h) << 16);
}

// ---------------------------------------------------------------------------
// K0: prep.
// Wt_fc[144][128] bf16 = [W_fc^T ; (W_fc@attn_l)^T ; (W_fc@attn_r)^T].
// Wt_cb[128][256] bf16 = theta*W_comb^T + c1*I(k==c) + c2*I(k==c+128)
// bvec[128] f32 = theta*(gat_bias @ W_comb_top) + c1*gat_bias
//   -- full GCNII blend + bias folded into GEMM weights (exact algebra);
//   combine epilogue is acc + bvec[col] + input.
// ---------------------------------------------------------------------------
__global__ __launch_bounds__(256) void prep_kernel(
    const float* __restrict__ W_fc, const float* __restrict__ attn_l,
    const float* __restrict__ attn_r, const float* __restrict__ W_comb,
    const float* __restrict__ gat_bias,
    const int* __restrict__ l_p, const float* __restrict__ lamda_p,
    const float* __restrict__ alpha_p,
    unsigned short* __restrict__ Wt_fc, unsigned short* __restrict__ Wt_cb,
    float* __restrict__ bvec)
{
    const float alpha = alpha_p[0];
    const float theta = fminf(1.0f, logf(lamda_p[0] / (float)l_p[0] + 1.0f));
    const float c1 = (1.f - theta) * (1.f - alpha);
    const float c2 = (1.f - theta) * alpha;

    const int t = blockIdx.x * 256 + threadIdx.x;
    const int stride = gridDim.x * 256;
    for (int i = t; i < 128 * 128; i += stride) {
        const int c = i >> 7, k = i & 127;
        Wt_fc[c * 128 + k] = f2bf(W_fc[k * 128 + c]);
    }
    for (int i = t; i < 8 * 128; i += stride) {
        const int hd = i >> 7, k = i & 127;
        float sl = 0.f, sr = 0.f;
        for (int d = 0; d < 16; ++d) {
            const float w = W_fc[k * 128 + hd * 16 + d];
            sl += w * attn_l[hd * 16 + d];
            sr += w * attn_r[hd * 16 + d];
        }
        Wt_fc[(128 + hd) * 128 + k] = f2bf(sl);
        Wt_fc[(136 + hd) * 128 + k] = f2bf(sr);
    }
    for (int i = t; i < 128 * 256; i += stride) {
        const int c = i >> 8, k = i & 255;
        float w = theta * W_comb[k * 128 + c];
        if (k == c) w += c1;
        if (k == c + 128) w += c2;
        Wt_cb[c * 256 + k] = f2bf(w);
    }
    for (int c = t; c < 128; c += stride) {
        float s = c1 * gat_bias[c];
        for (int k = 0; k < 128; ++k)
            s += theta * gat_bias[k] * W_comb[k * 128 + c];
        bvec[c] = s;
    }
}

// ---------------------------------------------------------------------------
// K1: h = input @ W_fc via bf16 MFMA, el/er as extra output columns.
// 64-row tile, 4 waves, 9 col-tiles, pad 36 (conflict-free frag reads).
// ---------------------------------------------------------------------------
__global__ __launch_bounds__(256) void fc_gemm_kernel(
    const float* __restrict__ A, const unsigned short* __restrict__ Wt,
    unsigned short* __restrict__ h, float* __restrict__ el,
    float* __restrict__ er, int n)
{
    __shared__ unsigned short As[64][36];
    __shared__ unsigned short Bs[144][36];
    const int tid = threadIdx.x;
    const int wave = tid >> 6;
    const int lane = tid & 63;
    const int m16 = lane & 15;
    const int kg = lane >> 4;
    const int rowBase = blockIdx.x * 64;

    f32x4 acc[9];
#pragma unroll
    for (int t = 0; t < 9; ++t) acc[t] = (f32x4){0.f, 0.f, 0.f, 0.f};

    const int rS = tid >> 2;
    const int pS = tid & 3;

    for (int ci = 0; ci < 4; ++ci) {
        const int kc = ci * 32;
        if (ci) __syncthreads();
        {
            int row = rowBase + rS;
            if (row >= n) row = n - 1;
            const float4 v0 = *(const float4*)&A[(long long)row * 128 + kc + pS * 8];
            const float4 v1 = *(const float4*)&A[(long long)row * 128 + kc + pS * 8 + 4];
            bf16x8 pk;
            pk[0] = (short)f2bf(v0.x); pk[1] = (short)f2bf(v0.y);
            pk[2] = (short)f2bf(v0.z); pk[3] = (short)f2bf(v0.w);
            pk[4] = (short)f2bf(v1.x); pk[5] = (short)f2bf(v1.y);
            pk[6] = (short)f2bf(v1.z); pk[7] = (short)f2bf(v1.w);
            *(bf16x8*)&As[rS][pS * 8] = pk;
        }
        for (int i = tid; i < 576; i += 256) {
            const int r = i >> 2, p = i & 3;
            *(bf16x8*)&Bs[r][p * 8] =
                *(const bf16x8*)&Wt[r * 128 + kc + p * 8];
        }
        __syncthreads();

        const bf16x8 afrag = *(const bf16x8*)&As[wave * 16 + m16][kg * 8];
#pragma unroll
        for (int t = 0; t < 9; ++t) {
            const bf16x8 bfrag = *(const bf16x8*)&Bs[t * 16 + m16][kg * 8];
            acc[t] = __builtin_amdgcn_mfma_f32_16x16x32_bf16(afrag, bfrag, acc[t], 0, 0, 0);
        }
    }

    const int r0 = rowBase + wave * 16 + kg * 4;
#pragma unroll
    for (int t = 0; t < 8; ++t) {
#pragma unroll
        for (int j = 0; j < 4; ++j) {
            const int row = r0 + j;
            if (row < n)
                h[(long long)row * 128 + t * 16 + m16] = f2bf(acc[t][j]);
        }
    }
#pragma unroll
    for (int j = 0; j < 4; ++j) {
        const int row = r0 + j;
        if (row < n) {
            const float v = acc[8][j];
            if (m16 < 8) el[(long long)row * 8 + m16] = v;
            else         er[(long long)row * 8 + (m16 - 8)] = v;
        }
    }
}

// ---------------------------------------------------------------------------
// CSR build: histogram -> 2-level exclusive scan -> scatter src ids by dst.
// ---------------------------------------------------------------------------
__global__ __launch_bounds__(256) void hist_kernel(
    const int* __restrict__ dst, int* __restrict__ deg, int E)
{
    const int i = blockIdx.x * 256 + threadIdx.x;
    if (i < E) atomicAdd(&deg[dst[i]], 1);
}

__global__ __launch_bounds__(256) void scan1_kernel(
    const int* __restrict__ deg, int* __restrict__ row,
    int* __restrict__ blockSums, int n)
{
    __shared__ int sdata[256];
    const int t = threadIdx.x;
    const int base = blockIdx.x * 1024 + t * 4;
    int v[4];
    int tot = 0;
#pragma unroll
    for (int j = 0; j < 4; ++j) {
        v[j] = (base + j < n) ? deg[base + j] : 0;
        tot += v[j];
    }
    sdata[t] = tot;
    __syncthreads();
    for (int off = 1; off < 256; off <<= 1) {
        const int x = (t >= off) ? sdata[t - off] : 0;
        __syncthreads();
        sdata[t] += x;
        __syncthreads();
    }
    if (t == 255) blockSums[blockIdx.x] = sdata[255];
    int run = sdata[t] - tot;
#pragma unroll
    for (int j = 0; j < 4; ++j) {
        if (base + j < n) row[base + j] = run;
        run += v[j];
    }
}

__global__ __launch_bounds__(128) void scan2_kernel(
    int* __restrict__ blockSums, int nb)
{
    __shared__ int sdata[128];
    const int t = threadIdx.x;
    const int v = (t < nb) ? blockSums[t] : 0;
    sdata[t] = v;
    __syncthreads();
    for (int off = 1; off < 128; off <<= 1) {
        const int x = (t >= off) ? sdata[t - off] : 0;
        __syncthreads();
        sdata[t] += x;
        __syncthreads();
    }
    if (t < nb) blockSums[t] = sdata[t] - v;
}

__global__ __launch_bounds__(256) void scan3_kernel(
    int* __restrict__ row, int* __restrict__ cursor,
    const int* __restrict__ blockSums, int n, int E)
{
    const int i = blockIdx.x * 256 + threadIdx.x;
    if (i == 0) row[n] = E;
    if (i >= n) return;
    const int r = row[i] + blockSums[i >> 10];
    row[i] = r;
    cursor[i] = r;
}

__global__ __launch_bounds__(256) void scatter_kernel(
    const int* __restrict__ src, const int* __restrict__ dst,
    int* __restrict__ cursor, int* __restrict__ srcs, int E)
{
    const int i = blockIdx.x * 256 + threadIdx.x;
    if (i >= E) return;
    const int pos = atomicAdd(&cursor[dst[i]], 1);
    srcs[pos] = src[i];
}

// ---------------------------------------------------------------------------
// K3: aggregate. One wave per dst node, ushort2 (2 features)/lane, one head
// per lane (hd = lane>>3). Cooperative srcs batch-load + shfl broadcast
// removes the dependent per-edge index load; unroll x2 keeps 2 gathers in
// flight. Local softmax, no atomics. rst written as bf16.
// ---------------------------------------------------------------------------
__global__ __launch_bounds__(256) void aggregate_kernel(
    const float* __restrict__ el, const float* __restrict__ er,
    const unsigned short* __restrict__ h, const int* __restrict__ row,
    const int* __restrict__ srcs, unsigned short* __restrict__ rst, int n)
{
    const int d = blockIdx.x * 4 + (threadIdx.x >> 6);
    const int lane = threadIdx.x & 63;
    if (d >= n) return;
    const int start = row[d], end = row[d + 1];
    const int hd = lane >> 3;
    const float erd = er[(long long)d * 8 + hd];

    float acc0 = 0.f, acc1 = 0.f, den = 0.f;
    for (int p = start; p < end; p += 64) {
        const int cnt = min(64, end - p);
        const int sv = srcs[p + (lane < cnt ? lane : cnt - 1)];
        int j = 0;
        for (; j + 1 < cnt; j += 2) {
            const int s0 = __shfl(sv, j);
            const int s1 = __shfl(sv, j + 1);
            const float g0 = el[(long long)s0 * 8 + hd];
            const float g1 = el[(long long)s1 * 8 + hd];
            const unsigned int u0 = *(const unsigned int*)&h[(long long)s0 * 128 + lane * 2];
            const unsigned int u1 = *(const unsigned int*)&h[(long long)s1 * 128 + lane * 2];
            float e0 = g0 + erd; e0 = e0 >= 0.f ? e0 : NEG_SLOPE * e0;
            float e1 = g1 + erd; e1 = e1 >= 0.f ? e1 : NEG_SLOPE * e1;
            const float w0 = __expf(e0);
            const float w1 = __expf(e1);
            den += w0 + w1;
            acc0 += w0 * __uint_as_float(u0 << 16)
                  + w1 * __uint_as_float(u1 << 16);
            acc1 += w0 * __uint_as_float(u0 & 0xffff0000u)
                  + w1 * __uint_as_float(u1 & 0xffff0000u);
        }
        if (j < cnt) {
            const int s0 = __shfl(sv, j);
            const unsigned int u0 = *(const unsigned int*)&h[(long long)s0 * 128 + lane * 2];
            float e0 = el[(long long)s0 * 8 + hd] + erd;
            e0 = e0 >= 0.f ? e0 : NEG_SLOPE * e0;
            const float w0 = __expf(e0);
            den += w0;
            acc0 += w0 * __uint_as_float(u0 << 16);
            acc1 += w0 * __uint_as_float(u0 & 0xffff0000u);
        }
    }
    ushort2 o;
    if (end > start) {
        const float inv = 1.f / den;
        o.x = f2bf(acc0 * inv);
        o.y = f2bf(acc1 * inv);
    } else {
        o.x = 0; o.y = 0;
    }
    *(ushort2*)&rst[(long long)d * 128 + lane * 2] = o;
}

// ---------------------------------------------------------------------------
// K4: GCNII combine via bf16 MFMA with fully-folded Wmod + bvec:
// out = acc + bvec[col] + input. rst is bf16 (A-stage chunks 0-3 are a pure
// copy). Single-barrier double-buffered staging (round-10 structure).
// ---------------------------------------------------------------------------
__global__ __launch_bounds__(256) void combine_gemm_kernel(
    const unsigned short* __restrict__ rst, const float* __restrict__ h0,
    const float* __restrict__ input, const unsigned short* __restrict__ Wt,
    const float* __restrict__ bvec, float* __restrict__ x, int n)
{
    __shared__ unsigned short As[2][64][36];
    __shared__ unsigned short Bs[2][128][36];
    const int tid = threadIdx.x;
    const int wave = tid >> 6;
    const int lane = tid & 63;
    const int m16 = lane & 15;
    const int kg = lane >> 4;
    const int rowBase = blockIdx.x * 64;

    f32x4 acc[8];
#pragma unroll
    for (int t = 0; t < 8; ++t) acc[t] = (f32x4){0.f, 0.f, 0.f, 0.f};

    const int rS = tid >> 2;           // A-stage row 0..63
    const int pS = tid & 3;            // A-stage 8-elem part
    const int rB = tid >> 1;           // B-stage row 0..127
    const int p0 = (tid & 1) * 2;      // B-stage parts p0, p0+1

    float4 va0, va1;
    bf16x8 vr, vb0, vb1;
    int arow = rowBase + rS;
    if (arow >= n) arow = n - 1;
    const long long aoff = (long long)arow * 128;

#define CB_LOAD(ci)                                                           \
    {                                                                         \
        const int kc = (ci) * 32;                                             \
        const int koff = kc & 127;                                            \
        if ((ci) < 4) {                                                       \
            vr = *(const bf16x8*)&rst[aoff + koff + pS * 8];                  \
        } else {                                                              \
            va0 = *(const float4*)&h0[aoff + koff + pS * 8];                  \
            va1 = *(const float4*)&h0[aoff + koff + pS * 8 + 4];              \
        }                                                                     \
        vb0 = *(const bf16x8*)&Wt[rB * 256 + kc + p0 * 8];                    \
        vb1 = *(const bf16x8*)&Wt[rB * 256 + kc + p0 * 8 + 8];                \
    }

#define CB_WRITE(buf, ci)                                                     \
    {                                                                         \
        if ((ci) < 4) {                                                       \
            *(bf16x8*)&As[buf][rS][pS * 8] = vr;                              \
        } else {                                                              \
            bf16x8 pk;                                                        \
            pk[0] = (short)f2bf(va0.x); pk[1] = (short)f2bf(va0.y);           \
            pk[2] = (short)f2bf(va0.z); pk[3] = (short)f2bf(va0.w);           \
            pk[4] = (short)f2bf(va1.x); pk[5] = (short)f2bf(va1.y);           \
            pk[6] = (short)f2bf(va1.z); pk[7] = (short)f2bf(va1.w);           \
            *(bf16x8*)&As[buf][rS][pS * 8] = pk;                              \
        }                                                                     \
        *(bf16x8*)&Bs[buf][rB][p0 * 8] = vb0;                                 \
        *(bf16x8*)&Bs[buf][rB][p0 * 8 + 8] = vb1;                             \
    }

    CB_LOAD(0)
    CB_WRITE(0, 0)
    __syncthreads();

#pragma unroll
    for (int ci = 0; ci < 8; ++ci) {
        const int cur = ci & 1;
        if (ci < 7) CB_LOAD(ci + 1)
        const bf16x8 afrag = *(const bf16x8*)&As[cur][wave * 16 + m16][kg * 8];
#pragma unroll
        for (int t = 0; t < 8; ++t) {
            const bf16x8 bfrag = *(const bf16x8*)&Bs[cur][t * 16 + m16][kg * 8];
            acc[t] = __builtin_amdgcn_mfma_f32_16x16x32_bf16(afrag, bfrag, acc[t], 0, 0, 0);
        }
        if (ci < 7) {
            CB_WRITE(cur ^ 1, ci + 1)
            __syncthreads();
        }
    }
#undef CB_LOAD
#undef CB_WRITE

    const int r0 = rowBase + wave * 16 + kg * 4;
#pragma unroll
    for (int t = 0; t < 8; ++t) {
        const int col = t * 16 + m16;
        const float bv = bvec[col];
#pragma unroll
        for (int j = 0; j < 4; ++j) {
            const int row = r0 + j;
            if (row < n) {
                const long long off = (long long)row * 128 + col;
                x[off] = acc[t][j] + bv + input[off];
            }
        }
    }
}

// ---------------------------------------------------------------------------
// K5: per-subgraph partial sums (split over nodes, atomics into (B,128)).
// ---------------------------------------------------------------------------
__global__ __launch_bounds__(128) void stats_kernel(
    const float* __restrict__ x, const int* __restrict__ cums,
    float* __restrict__ sums, float* __restrict__ sumsq)
{
    const int b = blockIdx.x / STATS_SPLIT;
    const int part = blockIdx.x % STATS_SPLIT;
    const int tid = threadIdx.x;
    const int start = cums[b], end = cums[b + 1];
    float s = 0.f, s2 = 0.f;
    for (int node = start + part; node < end; node += STATS_SPLIT) {
        const float v = x[(long long)node * 128 + tid];
        s += v;
        s2 += v * v;
    }
    atomicAdd(&sums[b * 128 + tid], s);
    atomicAdd(&sumsq[b * 128 + tid], s2);
}

__global__ __launch_bounds__(128) void finalize_stats_kernel(
    const int* __restrict__ cums, float* __restrict__ sums,
    float* __restrict__ sumsq)
{
    const int b = blockIdx.x;
    const int tid = threadIdx.x;
    const float cnt = (float)(cums[b + 1] - cums[b]);
    const float s = sums[b * 128 + tid];
    const float s2 = sumsq[b * 128 + tid];
    const float mean = s / cnt;
    float var = (s2 - s * mean) / (cnt - 1.f);
    var = fmaxf(var, 0.f);
    sums[b * 128 + tid] = mean;
    sumsq[b * 128 + tid] = 1.f / (sqrtf(var) + 1e-5f);
}

__global__ __launch_bounds__(256) void norm_kernel(
    const float* __restrict__ x, const float* __restrict__ mean,
    const float* __restrict__ istd, const int* __restrict__ cums, int nb,
    const float* __restrict__ gamma, const float* __restrict__ beta,
    float* __restrict__ out, int n)
{
    const long long gid = (long long)blockIdx.x * 256 + threadIdx.x;
    const int node = (int)(gid >> 5);
    if (node >= n) return;
    const int f4 = (int)(gid & 31);
    int lo = 0, hi = nb;
    while (hi - lo > 1) {
        const int mid = (lo + hi) >> 1;
        if (cums[mid] <= node) lo = mid; else hi = mid;
    }
    const float4 m = *(const float4*)&mean[lo * 128 + f4 * 4];
    const float4 is = *(const float4*)&istd[lo * 128 + f4 * 4];
    const float4 g = *(const float4*)&gamma[f4 * 4];
    const float4 bt = *(const float4*)&beta[f4 * 4];
    const float4 v = *(const float4*)&x[(long long)node * 128 + f4 * 4];
    float4 o;
    o.x = g.x * ((v.x - m.x) * is.x) + bt.x;
    o.y = g.y * ((v.y - m.y) * is.y) + bt.y;
    o.z = g.z * ((v.z - m.z) * is.z) + bt.z;
    o.w = g.w * ((v.w - m.w) * is.w) + bt.w;
    *(float4*)&out[(long long)node * 128 + f4 * 4] = o;
}

// ---------------------------------------------------------------------------
extern "C" void kernel_launch(void* const* d_in, const int* in_sizes, int n_in,
                              void* d_out, int out_size, void* d_ws, size_t ws_size,
                              hipStream_t stream) {
    const float* input   = (const float*)d_in[0];
    const float* h0      = (const float*)d_in[1];
    const int*   src     = (const int*)d_in[2];
    const int*   dst     = (const int*)d_in[3];
    const int*   cums    = (const int*)d_in[4];
    const int*   l_p     = (const int*)d_in[5];
    const float* lamda_p = (const float*)d_in[6];
    const float* alpha_p = (const float*)d_in[7];
    const float* W_fc    = (const float*)d_in[8];
    const float* attn_l  = (const float*)d_in[9];
    const float* attn_r  = (const float*)d_in[10];
    const float* gat_bias= (const float*)d_in[11];
    const float* W_comb  = (const float*)d_in[12];
    const float* gamma   = (const float*)d_in[13];
    const float* beta    = (const float*)d_in[14];

    const int n  = in_sizes[0] / 128;
    const int E  = in_sizes[2];
    const int nb = in_sizes[4] - 1;
    float* out = (float*)d_out;

    // workspace layout (all offsets 16B-aligned)
    char* ws = (char*)d_ws;
    size_t o = 0;
#define ALLOC(ptr, type, count)                                              \
    type* ptr = (type*)(ws + o); o = (o + (size_t)(count) * sizeof(type) + 15) & ~(size_t)15;
    ALLOC(h,        unsigned short, (size_t)n * 128)
    ALLOC(el,       float,          (size_t)n * 8)
    ALLOC(er,       float,          (size_t)n * 8)
    ALLOC(rst,      unsigned short, (size_t)n * 128)
    ALLOC(sums,     float,          (size_t)nb * 128)
    ALLOC(sumsq,    float,          (size_t)nb * 128)
    ALLOC(deg,      int,            (size_t)n)
    ALLOC(row_ptr,  int,            (size_t)n + 1)
    ALLOC(cursor,   int,            (size_t)n)
    ALLOC(blockSums,int,            128)
    ALLOC(srcs,     int,            (size_t)E)
    ALLOC(Wt_fc,    unsigned short, 144 * 128)
    ALLOC(Wt_cb,    unsigned short, 128 * 256)
    ALLOC(bvec,     float,          128)
#undef ALLOC

    hipMemsetAsync(deg, 0, (size_t)n * 4, stream);
    hipMemsetAsync(sums, 0, (size_t)nb * 128 * 4, stream);
    hipMemsetAsync(sumsq, 0, (size_t)nb * 128 * 4, stream);

    // --- prep (weights -> bf16 transposed; attn columns + GCNII/bias fold) ---
    prep_kernel<<<64, 256, 0, stream>>>(
        W_fc, attn_l, attn_r, W_comb, gat_bias, l_p, lamda_p, alpha_p,
        Wt_fc, Wt_cb, bvec);

    // --- CSR build ---
    hist_kernel<<<(E + 255) / 256, 256, 0, stream>>>(dst, deg, E);
    const int nblk1 = (n + 1023) / 1024;
    scan1_kernel<<<nblk1, 256, 0, stream>>>(deg, row_ptr, blockSums, n);
    scan2_kernel<<<1, 128, 0, stream>>>(blockSums, nblk1);
    scan3_kernel<<<(n + 255) / 256, 256, 0, stream>>>(row_ptr, cursor, blockSums, n, E);
    scatter_kernel<<<(E + 255) / 256, 256, 0, stream>>>(src, dst, cursor, srcs, E);

    // --- dense pipeline ---
    const int gemm_grid = (n + 63) / 64;
    fc_gemm_kernel<<<gemm_grid, 256, 0, stream>>>(input, Wt_fc, h, el, er, n);

    aggregate_kernel<<<(n + 3) / 4, 256, 0, stream>>>(
        el, er, h, row_ptr, srcs, rst, n);

    combine_gemm_kernel<<<gemm_grid, 256, 0, stream>>>(
        rst, h0, input, Wt_cb, bvec, out, n);

    stats_kernel<<<nb * STATS_SPLIT, 128, 0, stream>>>(out, cums, sums, sumsq);
    finalize_stats_kernel<<<nb, 128, 0, stream>>>(cums, sums, sumsq);

    const long long norm_threads = (long long)n * 32;
    norm_kernel<<<(int)((norm_threads + 255) / 256), 256, 0, stream>>>(
        out, sums, sumsq, cums, nb, gamma, beta, out, n);
}

// Round 12
// 225.753 us; speedup vs baseline: 1.7534x; 1.0919x over previous
//
#include <hip/hip_runtime.h>
#include <hip/hip_bf16.h>

#define NEG_SLOPE 0.2f

typedef short bf16x8 __attribute__((ext_vector_type(8)));
typedef float f32x4 __attribute__((ext_vector_type(4)));

__device__ __forceinline__ unsigned short f2bf(float f) {
    unsigned int u = __float_as_uint(f);
    unsigned int r = (u + 0x7fffu + ((u >> 16) & 1u)) >> 16;
    return (unsigned short)r;
}
__device__ __forceinline__ float bf2f(unsigned short h) {
    return __uint_as_float(((unsigned int)h) << 16);
}

// ---------------------------------------------------------------------------
// K0: prep. Wt_fc[144][128] = [W_fc^T ; (W_fc@attn_l)^T ; (W_fc@attn_r)^T].
// Wt_cb[128][256] = theta*W_comb^T + c1*I(k==c) + c2*I(k==c+128).
// bvec[128] = theta*(gat_bias @ W_comb_top) + c1*gat_bias.
// ---------------------------------------------------------------------------
__global__ __launch_bounds__(256) void prep_kernel(
    const float* __restrict__ W_fc, const float* __restrict__ attn_l,
    const float* __restrict__ attn_r, const float* __restrict__ W_comb,
    const float* __restrict__ gat_bias,
    const int* __restrict__ l_p, const float* __restrict__ lamda_p,
    const float* __restrict__ alpha_p,
    unsigned short* __restrict__ Wt_fc, unsigned short* __restrict__ Wt_cb,
    float* __restrict__ bvec)
{
    const float alpha = alpha_p[0];
    const float theta = fminf(1.0f, logf(lamda_p[0] / (float)l_p[0] + 1.0f));
    const float c1 = (1.f - theta) * (1.f - alpha);
    const float c2 = (1.f - theta) * alpha;

    const int t = blockIdx.x * 256 + threadIdx.x;
    const int stride = gridDim.x * 256;
    for (int i = t; i < 128 * 128; i += stride) {
        const int c = i >> 7, k = i & 127;
        Wt_fc[c * 128 + k] = f2bf(W_fc[k * 128 + c]);
    }
    for (int i = t; i < 8 * 128; i += stride) {
        const int hd = i >> 7, k = i & 127;
        float sl = 0.f, sr = 0.f;
        for (int d = 0; d < 16; ++d) {
            const float w = W_fc[k * 128 + hd * 16 + d];
            sl += w * attn_l[hd * 16 + d];
            sr += w * attn_r[hd * 16 + d];
        }
        Wt_fc[(128 + hd) * 128 + k] = f2bf(sl);
        Wt_fc[(136 + hd) * 128 + k] = f2bf(sr);
    }
    for (int i = t; i < 128 * 256; i += stride) {
        const int c = i >> 8, k = i & 255;
        float w = theta * W_comb[k * 128 + c];
        if (k == c) w += c1;
        if (k == c + 128) w += c2;
        Wt_cb[c * 256 + k] = f2bf(w);
    }
    for (int c = t; c < 128; c += stride) {
        float s = c1 * gat_bias[c];
        for (int k = 0; k < 128; ++k)
            s += theta * gat_bias[k] * W_comb[k * 128 + c];
        bvec[c] = s;
    }
}

// ---------------------------------------------------------------------------
// K1: h = input @ W_fc via bf16 MFMA, el/er as output cols 128..143.
// A-fragments for ALL 4 k-chunks live in registers (loaded once at start ->
// HBM latency amortized); LDS holds only the B double-buffer.
// ---------------------------------------------------------------------------
__global__ __launch_bounds__(256) void fc_gemm_kernel(
    const float* __restrict__ A, const unsigned short* __restrict__ Wt,
    unsigned short* __restrict__ h, float* __restrict__ el,
    float* __restrict__ er, int n)
{
    __shared__ unsigned short Bs[2][144][36];
    const int tid = threadIdx.x;
    const int wave = tid >> 6;
    const int lane = tid & 63;
    const int m16 = lane & 15;
    const int kg = lane >> 4;
    const int rowBase = blockIdx.x * 64;

    // ---- A in registers: all 4 chunks, issued immediately ----
    int arow = rowBase + wave * 16 + m16;
    if (arow >= n) arow = n - 1;
    const long long aoff = (long long)arow * 128;
    bf16x8 af[4];
#pragma unroll
    for (int ci = 0; ci < 4; ++ci) {
        const float4 v0 = *(const float4*)&A[aoff + ci * 32 + kg * 8];
        const float4 v1 = *(const float4*)&A[aoff + ci * 32 + kg * 8 + 4];
        bf16x8 pk;
        pk[0] = (short)f2bf(v0.x); pk[1] = (short)f2bf(v0.y);
        pk[2] = (short)f2bf(v0.z); pk[3] = (short)f2bf(v0.w);
        pk[4] = (short)f2bf(v1.x); pk[5] = (short)f2bf(v1.y);
        pk[6] = (short)f2bf(v1.z); pk[7] = (short)f2bf(v1.w);
        af[ci] = pk;
    }

    // ---- B staging: 144 rows x 32 k per chunk = 288 16B-units ----
    const int rB = tid >> 1;
    const int p0 = (tid & 1) * 2;
    const bool hasU2 = tid < 32;
    const int rB2 = 128 + (tid >> 1);

    bf16x8 vb0, vb1, w0, w1;
#define FC_BLOAD(ci)                                                         \
    {                                                                        \
        const int kc = (ci) * 32;                                            \
        vb0 = *(const bf16x8*)&Wt[rB * 128 + kc + p0 * 8];                   \
        vb1 = *(const bf16x8*)&Wt[rB * 128 + kc + p0 * 8 + 8];               \
        if (hasU2) {                                                         \
            w0 = *(const bf16x8*)&Wt[rB2 * 128 + kc + p0 * 8];               \
            w1 = *(const bf16x8*)&Wt[rB2 * 128 + kc + p0 * 8 + 8];           \
        }                                                                    \
    }
#define FC_BWRITE(buf)                                                       \
    {                                                                        \
        *(bf16x8*)&Bs[buf][rB][p0 * 8] = vb0;                                \
        *(bf16x8*)&Bs[buf][rB][p0 * 8 + 8] = vb1;                            \
        if (hasU2) {                                                         \
            *(bf16x8*)&Bs[buf][rB2][p0 * 8] = w0;                            \
            *(bf16x8*)&Bs[buf][rB2][p0 * 8 + 8] = w1;                        \
        }                                                                    \
    }

    f32x4 acc[9];
#pragma unroll
    for (int t = 0; t < 9; ++t) acc[t] = (f32x4){0.f, 0.f, 0.f, 0.f};

    FC_BLOAD(0)
    FC_BWRITE(0)
    __syncthreads();

#pragma unroll
    for (int ci = 0; ci < 4; ++ci) {
        const int cur = ci & 1;
        if (ci < 3) FC_BLOAD(ci + 1)
#pragma unroll
        for (int t = 0; t < 9; ++t) {
            const bf16x8 bfrag = *(const bf16x8*)&Bs[cur][t * 16 + m16][kg * 8];
            acc[t] = __builtin_amdgcn_mfma_f32_16x16x32_bf16(af[ci], bfrag, acc[t], 0, 0, 0);
        }
        if (ci < 3) {
            FC_BWRITE(cur ^ 1)
            __syncthreads();
        }
    }
#undef FC_BLOAD
#undef FC_BWRITE

    const int r0 = rowBase + wave * 16 + kg * 4;
#pragma unroll
    for (int t = 0; t < 8; ++t) {
#pragma unroll
        for (int j = 0; j < 4; ++j) {
            const int row = r0 + j;
            if (row < n)
                h[(long long)row * 128 + t * 16 + m16] = f2bf(acc[t][j]);
        }
    }
#pragma unroll
    for (int j = 0; j < 4; ++j) {
        const int row = r0 + j;
        if (row < n) {
            const float v = acc[8][j];
            if (m16 < 8) el[(long long)row * 8 + m16] = v;
            else         er[(long long)row * 8 + (m16 - 8)] = v;
        }
    }
}

// ---------------------------------------------------------------------------
// CSR build: histogram -> 2-level exclusive scan -> scatter src ids by dst.
// ---------------------------------------------------------------------------
__global__ __launch_bounds__(256) void hist_kernel(
    const int* __restrict__ dst, int* __restrict__ deg, int E)
{
    const int i = blockIdx.x * 256 + threadIdx.x;
    if (i < E) atomicAdd(&deg[dst[i]], 1);
}

__global__ __launch_bounds__(256) void scan1_kernel(
    const int* __restrict__ deg, int* __restrict__ row,
    int* __restrict__ blockSums, int n)
{
    __shared__ int sdata[256];
    const int t = threadIdx.x;
    const int base = blockIdx.x * 1024 + t * 4;
    int v[4];
    int tot = 0;
#pragma unroll
    for (int j = 0; j < 4; ++j) {
        v[j] = (base + j < n) ? deg[base + j] : 0;
        tot += v[j];
    }
    sdata[t] = tot;
    __syncthreads();
    for (int off = 1; off < 256; off <<= 1) {
        const int x = (t >= off) ? sdata[t - off] : 0;
        __syncthreads();
        sdata[t] += x;
        __syncthreads();
    }
    if (t == 255) blockSums[blockIdx.x] = sdata[255];
    int run = sdata[t] - tot;
#pragma unroll
    for (int j = 0; j < 4; ++j) {
        if (base + j < n) row[base + j] = run;
        run += v[j];
    }
}

__global__ __launch_bounds__(128) void scan2_kernel(
    int* __restrict__ blockSums, int nb)
{
    __shared__ int sdata[128];
    const int t = threadIdx.x;
    const int v = (t < nb) ? blockSums[t] : 0;
    sdata[t] = v;
    __syncthreads();
    for (int off = 1; off < 128; off <<= 1) {
        const int x = (t >= off) ? sdata[t - off] : 0;
        __syncthreads();
        sdata[t] += x;
        __syncthreads();
    }
    if (t < nb) blockSums[t] = sdata[t] - v;
}

__global__ __launch_bounds__(256) void scan3_kernel(
    int* __restrict__ row, int* __restrict__ cursor,
    const int* __restrict__ blockSums, int n, int E)
{
    const int i = blockIdx.x * 256 + threadIdx.x;
    if (i == 0) row[n] = E;
    if (i >= n) return;
    const int r = row[i] + blockSums[i >> 10];
    row[i] = r;
    cursor[i] = r;
}

__global__ __launch_bounds__(256) void scatter_kernel(
    const int* __restrict__ src, const int* __restrict__ dst,
    int* __restrict__ cursor, int* __restrict__ srcs, int E)
{
    const int i = blockIdx.x * 256 + threadIdx.x;
    if (i >= E) return;
    const int pos = atomicAdd(&cursor[dst[i]], 1);
    srcs[pos] = src[i];
}

// ---------------------------------------------------------------------------
// K3: aggregate. One wave per dst node, ushort2/lane, one head per lane,
// cooperative srcs batch + shfl broadcast, x2 unroll. rst written bf16.
// ---------------------------------------------------------------------------
__global__ __launch_bounds__(256) void aggregate_kernel(
    const float* __restrict__ el, const float* __restrict__ er,
    const unsigned short* __restrict__ h, const int* __restrict__ row,
    const int* __restrict__ srcs, unsigned short* __restrict__ rst, int n)
{
    const int d = blockIdx.x * 4 + (threadIdx.x >> 6);
    const int lane = threadIdx.x & 63;
    if (d >= n) return;
    const int start = row[d], end = row[d + 1];
    const int hd = lane >> 3;
    const float erd = er[(long long)d * 8 + hd];

    float acc0 = 0.f, acc1 = 0.f, den = 0.f;
    for (int p = start; p < end; p += 64) {
        const int cnt = min(64, end - p);
        const int sv = srcs[p + (lane < cnt ? lane : cnt - 1)];
        int j = 0;
        for (; j + 1 < cnt; j += 2) {
            const int s0 = __shfl(sv, j);
            const int s1 = __shfl(sv, j + 1);
            const float g0 = el[(long long)s0 * 8 + hd];
            const float g1 = el[(long long)s1 * 8 + hd];
            const unsigned int u0 = *(const unsigned int*)&h[(long long)s0 * 128 + lane * 2];
            const unsigned int u1 = *(const unsigned int*)&h[(long long)s1 * 128 + lane * 2];
            float e0 = g0 + erd; e0 = e0 >= 0.f ? e0 : NEG_SLOPE * e0;
            float e1 = g1 + erd; e1 = e1 >= 0.f ? e1 : NEG_SLOPE * e1;
            const float w0 = __expf(e0);
            const float w1 = __expf(e1);
            den += w0 + w1;
            acc0 += w0 * __uint_as_float(u0 << 16)
                  + w1 * __uint_as_float(u1 << 16);
            acc1 += w0 * __uint_as_float(u0 & 0xffff0000u)
                  + w1 * __uint_as_float(u1 & 0xffff0000u);
        }
        if (j < cnt) {
            const int s0 = __shfl(sv, j);
            const unsigned int u0 = *(const unsigned int*)&h[(long long)s0 * 128 + lane * 2];
            float e0 = el[(long long)s0 * 8 + hd] + erd;
            e0 = e0 >= 0.f ? e0 : NEG_SLOPE * e0;
            const float w0 = __expf(e0);
            den += w0;
            acc0 += w0 * __uint_as_float(u0 << 16);
            acc1 += w0 * __uint_as_float(u0 & 0xffff0000u);
        }
    }
    ushort2 o;
    if (end > start) {
        const float inv = 1.f / den;
        o.x = f2bf(acc0 * inv);
        o.y = f2bf(acc1 * inv);
    } else {
        o.x = 0; o.y = 0;
    }
    *(ushort2*)&rst[(long long)d * 128 + lane * 2] = o;
}

// ---------------------------------------------------------------------------
// K4: GCNII combine via bf16 MFMA, fully folded: out = acc + bvec + input.
// A-fragments for ALL 8 k-chunks in registers (rst bf16 direct, h0 cvt),
// loaded once at start. LDS = B double-buffer only. FUSED GraphNorm stats:
// per-thread partials -> shfl kg-reduce -> LDS pool -> atomics (block spans
// <= 2 subgraphs since 64 << subgraph size; rare cross rows go direct).
// ---------------------------------------------------------------------------
__global__ __launch_bounds__(256) void combine_gemm_kernel(
    const unsigned short* __restrict__ rst, const float* __restrict__ h0,
    const float* __restrict__ input, const unsigned short* __restrict__ Wt,
    const float* __restrict__ bvec, const int* __restrict__ cums, int nb,
    float* __restrict__ sums, float* __restrict__ sumsq,
    float* __restrict__ x, int n)
{
    __shared__ unsigned short Bs[2][128][36];
    __shared__ float s_sum[128], s_sq[128];
    const int tid = threadIdx.x;
    const int wave = tid >> 6;
    const int lane = tid & 63;
    const int m16 = lane & 15;
    const int kg = lane >> 4;
    const int rowBase = blockIdx.x * 64;

    if (tid < 128) { s_sum[tid] = 0.f; s_sq[tid] = 0.f; }

    // ---- A in registers: 8 chunks (rst 0-3 direct bf16, h0 4-7 cvt) ----
    int arow = rowBase + wave * 16 + m16;
    if (arow >= n) arow = n - 1;
    const long long aoff = (long long)arow * 128;
    bf16x8 af[8];
#pragma unroll
    for (int ci = 0; ci < 4; ++ci)
        af[ci] = *(const bf16x8*)&rst[aoff + ci * 32 + kg * 8];
#pragma unroll
    for (int ci = 0; ci < 4; ++ci) {
        const float4 v0 = *(const float4*)&h0[aoff + ci * 32 + kg * 8];
        const float4 v1 = *(const float4*)&h0[aoff + ci * 32 + kg * 8 + 4];
        bf16x8 pk;
        pk[0] = (short)f2bf(v0.x); pk[1] = (short)f2bf(v0.y);
        pk[2] = (short)f2bf(v0.z); pk[3] = (short)f2bf(v0.w);
        pk[4] = (short)f2bf(v1.x); pk[5] = (short)f2bf(v1.y);
        pk[6] = (short)f2bf(v1.z); pk[7] = (short)f2bf(v1.w);
        af[4 + ci] = pk;
    }

    const int rB = tid >> 1;
    const int p0 = (tid & 1) * 2;
    bf16x8 vb0, vb1;

    f32x4 acc[8];
#pragma unroll
    for (int t = 0; t < 8; ++t) acc[t] = (f32x4){0.f, 0.f, 0.f, 0.f};

    vb0 = *(const bf16x8*)&Wt[rB * 256 + p0 * 8];
    vb1 = *(const bf16x8*)&Wt[rB * 256 + p0 * 8 + 8];
    *(bf16x8*)&Bs[0][rB][p0 * 8] = vb0;
    *(bf16x8*)&Bs[0][rB][p0 * 8 + 8] = vb1;
    __syncthreads();

#pragma unroll
    for (int ci = 0; ci < 8; ++ci) {
        const int cur = ci & 1;
        if (ci < 7) {
            vb0 = *(const bf16x8*)&Wt[rB * 256 + (ci + 1) * 32 + p0 * 8];
            vb1 = *(const bf16x8*)&Wt[rB * 256 + (ci + 1) * 32 + p0 * 8 + 8];
        }
#pragma unroll
        for (int t = 0; t < 8; ++t) {
            const bf16x8 bfrag = *(const bf16x8*)&Bs[cur][t * 16 + m16][kg * 8];
            acc[t] = __builtin_amdgcn_mfma_f32_16x16x32_bf16(af[ci], bfrag, acc[t], 0, 0, 0);
        }
        if (ci < 7) {
            *(bf16x8*)&Bs[cur ^ 1][rB][p0 * 8] = vb0;
            *(bf16x8*)&Bs[cur ^ 1][rB][p0 * 8 + 8] = vb1;
            __syncthreads();
        }
    }

    // ---- epilogue: out = acc + bvec + input, fused GraphNorm partials ----
    // block subgraph: sid0 = segment of rowBase; boundary at cums[sid0+1]
    int lo = 0, hi = nb;
    while (hi - lo > 1) {
        const int mid = (lo + hi) >> 1;
        if (cums[mid] <= rowBase) lo = mid; else hi = mid;
    }
    const int sid0 = lo;
    const int bnd = cums[sid0 + 1];

    const int r0 = rowBase + wave * 16 + kg * 4;
#pragma unroll
    for (int t = 0; t < 8; ++t) {
        const int col = t * 16 + m16;
        const float bv = bvec[col];
        float s0 = 0.f, q0 = 0.f, s1 = 0.f, q1 = 0.f;
#pragma unroll
        for (int j = 0; j < 4; ++j) {
            const int row = r0 + j;
            if (row < n) {
                const long long off = (long long)row * 128 + col;
                const float val = acc[t][j] + bv + input[off];
                x[off] = val;
                if (row < bnd) { s0 += val; q0 += val * val; }
                else           { s1 += val; q1 += val * val; }
            }
        }
        // reduce across kg (lanes m16, m16+16, m16+32, m16+48)
        s0 += __shfl_xor(s0, 16, 64); s0 += __shfl_xor(s0, 32, 64);
        q0 += __shfl_xor(q0, 16, 64); q0 += __shfl_xor(q0, 32, 64);
        s1 += __shfl_xor(s1, 16, 64); s1 += __shfl_xor(s1, 32, 64);
        q1 += __shfl_xor(q1, 16, 64); q1 += __shfl_xor(q1, 32, 64);
        if (kg == 0) {
            atomicAdd(&s_sum[col], s0);
            atomicAdd(&s_sq[col], q0);
            if (s1 != 0.f || q1 != 0.f) {  // rare: boundary block
                atomicAdd(&sums[(sid0 + 1) * 128 + col], s1);
                atomicAdd(&sumsq[(sid0 + 1) * 128 + col], q1);
            }
        }
    }
    __syncthreads();
    if (tid < 128) {
        atomicAdd(&sums[sid0 * 128 + tid], s_sum[tid]);
        atomicAdd(&sumsq[sid0 * 128 + tid], s_sq[tid]);
    }
}

// K6: sums -> mean, sumsq -> 1/(std+eps)  (unbiased, n-1)
__global__ __launch_bounds__(128) void finalize_stats_kernel(
    const int* __restrict__ cums, float* __restrict__ sums,
    float* __restrict__ sumsq)
{
    const int b = blockIdx.x;
    const int tid = threadIdx.x;
    const float cnt = (float)(cums[b + 1] - cums[b]);
    const float s = sums[b * 128 + tid];
    const float s2 = sumsq[b * 128 + tid];
    const float mean = s / cnt;
    float var = (s2 - s * mean) / (cnt - 1.f);
    var = fmaxf(var, 0.f);
    sums[b * 128 + tid] = mean;
    sumsq[b * 128 + tid] = 1.f / (sqrtf(var) + 1e-5f);
}

__global__ __launch_bounds__(256) void norm_kernel(
    const float* __restrict__ x, const float* __restrict__ mean,
    const float* __restrict__ istd, const int* __restrict__ cums, int nb,
    const float* __restrict__ gamma, const float* __restrict__ beta,
    float* __restrict__ out, int n)
{
    const long long gid = (long long)blockIdx.x * 256 + threadIdx.x;
    const int node = (int)(gid >> 5);
    if (node >= n) return;
    const int f4 = (int)(gid & 31);
    int lo = 0, hi = nb;
    while (hi - lo > 1) {
        const int mid = (lo + hi) >> 1;
        if (cums[mid] <= node) lo = mid; else hi = mid;
    }
    const float4 m = *(const float4*)&mean[lo * 128 + f4 * 4];
    const float4 is = *(const float4*)&istd[lo * 128 + f4 * 4];
    const float4 g = *(const float4*)&gamma[f4 * 4];
    const float4 bt = *(const float4*)&beta[f4 * 4];
    const float4 v = *(const float4*)&x[(long long)node * 128 + f4 * 4];
    float4 o;
    o.x = g.x * ((v.x - m.x) * is.x) + bt.x;
    o.y = g.y * ((v.y - m.y) * is.y) + bt.y;
    o.z = g.z * ((v.z - m.z) * is.z) + bt.z;
    o.w = g.w * ((v.w - m.w) * is.w) + bt.w;
    *(float4*)&out[(long long)node * 128 + f4 * 4] = o;
}

// ---------------------------------------------------------------------------
extern "C" void kernel_launch(void* const* d_in, const int* in_sizes, int n_in,
                              void* d_out, int out_size, void* d_ws, size_t ws_size,
                              hipStream_t stream) {
    const float* input   = (const float*)d_in[0];
    const float* h0      = (const float*)d_in[1];
    const int*   src     = (const int*)d_in[2];
    const int*   dst     = (const int*)d_in[3];
    const int*   cums    = (const int*)d_in[4];
    const int*   l_p     = (const int*)d_in[5];
    const float* lamda_p = (const float*)d_in[6];
    const float* alpha_p = (const float*)d_in[7];
    const float* W_fc    = (const float*)d_in[8];
    const float* attn_l  = (const float*)d_in[9];
    const float* attn_r  = (const float*)d_in[10];
    const float* gat_bias= (const float*)d_in[11];
    const float* W_comb  = (const float*)d_in[12];
    const float* gamma   = (const float*)d_in[13];
    const float* beta    = (const float*)d_in[14];

    const int n  = in_sizes[0] / 128;
    const int E  = in_sizes[2];
    const int nb = in_sizes[4] - 1;
    float* out = (float*)d_out;

    // workspace layout (all offsets 16B-aligned)
    char* ws = (char*)d_ws;
    size_t o = 0;
#define ALLOC(ptr, type, count)                                              \
    type* ptr = (type*)(ws + o); o = (o + (size_t)(count) * sizeof(type) + 15) & ~(size_t)15;
    ALLOC(h,        unsigned short, (size_t)n * 128)
    ALLOC(el,       float,          (size_t)n * 8)
    ALLOC(er,       float,          (size_t)n * 8)
    ALLOC(rst,      unsigned short, (size_t)n * 128)
    ALLOC(sums,     float,          (size_t)nb * 128)
    ALLOC(sumsq,    float,          (size_t)nb * 128)
    ALLOC(deg,      int,            (size_t)n)
    ALLOC(row_ptr,  int,            (size_t)n + 1)
    ALLOC(cursor,   int,            (size_t)n)
    ALLOC(blockSums,int,            128)
    ALLOC(srcs,     int,            (size_t)E)
    ALLOC(Wt_fc,    unsigned short, 144 * 128)
    ALLOC(Wt_cb,    unsigned short, 128 * 256)
    ALLOC(bvec,     float,          128)
#undef ALLOC

    hipMemsetAsync(deg, 0, (size_t)n * 4, stream);
    hipMemsetAsync(sums, 0, (size_t)nb * 128 * 4, stream);
    hipMemsetAsync(sumsq, 0, (size_t)nb * 128 * 4, stream);

    // --- prep (weights -> bf16 transposed; attn columns + GCNII/bias fold) ---
    prep_kernel<<<64, 256, 0, stream>>>(
        W_fc, attn_l, attn_r, W_comb, gat_bias, l_p, lamda_p, alpha_p,
        Wt_fc, Wt_cb, bvec);

    // --- CSR build ---
    hist_kernel<<<(E + 255) / 256, 256, 0, stream>>>(dst, deg, E);
    const int nblk1 = (n + 1023) / 1024;
    scan1_kernel<<<nblk1, 256, 0, stream>>>(deg, row_ptr, blockSums, n);
    scan2_kernel<<<1, 128, 0, stream>>>(blockSums, nblk1);
    scan3_kernel<<<(n + 255) / 256, 256, 0, stream>>>(row_ptr, cursor, blockSums, n, E);
    scatter_kernel<<<(E + 255) / 256, 256, 0, stream>>>(src, dst, cursor, srcs, E);

    // --- dense pipeline ---
    const int gemm_grid = (n + 63) / 64;
    fc_gemm_kernel<<<gemm_grid, 256, 0, stream>>>(input, Wt_fc, h, el, er, n);

    aggregate_kernel<<<(n + 3) / 4, 256, 0, stream>>>(
        el, er, h, row_ptr, srcs, rst, n);

    combine_gemm_kernel<<<gemm_grid, 256, 0, stream>>>(
        rst, h0, input, Wt_cb, bvec, cums, nb, sums, sumsq, out, n);

    finalize_stats_kernel<<<nb, 128, 0, stream>>>(cums, sums, sumsq);

    const long long norm_threads = (long long)n * 32;
    norm_kernel<<<(int)((norm_threads + 255) / 256), 256, 0, stream>>>(
        out, sums, sumsq, cums, nb, gamma, beta, out, n);
}